// Round 4
// baseline (752.701 us; speedup 1.0000x reference)
//
#include <hip/hip_runtime.h>

typedef unsigned short ushort_t;
typedef short s8v __attribute__((ext_vector_type(8)));
typedef unsigned short ushort8 __attribute__((ext_vector_type(8)));
typedef float floatx4 __attribute__((ext_vector_type(4)));

#define MFMA16(a, b, c) __builtin_amdgcn_mfma_f32_16x16x32_bf16((a), (b), (c), 0, 0, 0)

static constexpr int B_SZ = 8;
static constexpr int L = 8192;
static constexpr int H = 1024;
static constexpr int M_TOT = B_SZ * L;        // 65536 rows
static constexpr int S_CH = 128;              // chunk length == gemm1 row-tile
static constexpr int NC = L / S_CH;           // 64 chunks per batch

// round-to-nearest-even fp32 -> bf16 bits
__device__ inline ushort_t f2bf(float f) {
    union { float f; unsigned u; } v; v.f = f;
    unsigned r = v.u + 0x7fffu + ((v.u >> 16) & 1u);
    return (ushort_t)(r >> 16);
}

// packed f32x2 -> bf16x2 (RNE) in one instruction
__device__ inline unsigned cvtpk(float lo, float hi) {
    unsigned r;
    asm("v_cvt_pk_bf16_f32 %0, %1, %2" : "=v"(r) : "v"(lo), "v"(hi));
    return r;
}

typedef union { s8v v; unsigned u[4]; } u32x4;

// async global->LDS, 16B per lane; lds dest = wave-uniform base + lane*16
__device__ inline void gload_lds16(const void* g, void* l) {
    __builtin_amdgcn_global_load_lds(
        (const __attribute__((address_space(1))) void*)g,
        (__attribute__((address_space(3))) void*)l, 16, 0, 0);
}

// ---------------------------------------------------------------- params ----
// params[0..63]=dA_r [64..127]=dA_i [128..191]=s_r [192..255]=s_i
// dApow INTERLEAVED: dApow[k*128 + 2p] = Re(dA^k), [k*128+2p+1] = Im(dA^k)
__global__ void params_kernel(const float* __restrict__ A_real,
                              const float* __restrict__ A_imag,
                              const float* __restrict__ inv_dt,
                              float* __restrict__ params,
                              float* __restrict__ dApow) {
    int p = threadIdx.x;  // 64 threads
    float x = inv_dt[p];
    float dt = (x > 20.f) ? x : log1pf(expf(x));
    float ar = A_real[p], ai = A_imag[p];
    float dr = 1.f - 0.5f * dt * ar;
    float di = -0.5f * dt * ai;
    float inv = 1.f / fmaf(dr, dr, di * di);
    float nr = 1.f + 0.5f * dt * ar, ni = 0.5f * dt * ai;
    float dAr = (nr * dr + ni * di) * inv;
    float dAi = (ni * dr - nr * di) * inv;
    params[p]       = dAr;
    params[64 + p]  = dAi;
    params[128 + p] = dt * dr * inv;    // Re(dt/den)
    params[192 + p] = -dt * di * inv;   // Im(dt/den)
    float pr = 1.f, pi = 0.f;
    dApow[2 * p] = 1.f; dApow[2 * p + 1] = 0.f;
    for (int k = 1; k <= S_CH; k++) {
        float npr = pr * dAr - pi * dAi;
        float npi = pr * dAi + pi * dAr;
        pr = npr; pi = npi;
        dApow[k * 128 + 2 * p]     = pr;
        dApow[k * 128 + 2 * p + 1] = pi;
    }
}

// -------------------------------------------------- build bf16 weights ----
// W1T LINEAR rows: W1T[2p][k] = Re(s_p*B[p][k]), W1T[2p+1][k] = Im(...)
// CeffT SWIZZLED granules (16B): byte(granule) = tile*8192 + g*16,
//   g = n*4 + (q ^ ((n>>1)&3)), tile = ct*4 + k/32, n = h%128, ct = h/128.
//   Ceff[h][2p] = 2*Cr[h][p], Ceff[h][2p+1] = -2*Ci[h][p].
__global__ void build_w(const float* __restrict__ Br, const float* __restrict__ Bi,
                        const float* __restrict__ Cr, const float* __restrict__ Ci,
                        const float* __restrict__ params,
                        ushort_t* __restrict__ W1T, ushort_t* __restrict__ CeffT) {
    int t = blockIdx.x * 256 + threadIdx.x;   // 147456 threads
    if (t < 128 * 1024) {
        int n = t >> 10, k = t & 1023;
        int p = n >> 1;
        float sr = params[128 + p], si = params[192 + p];
        float br = Br[p * 1024 + k], bi = Bi[p * 1024 + k];
        float v = (n & 1) ? (sr * bi + si * br) : (sr * br - si * bi);
        W1T[t] = f2bf(v);
    } else {
        int t2 = t - 128 * 1024;              // 16384 granule-threads
        int ct_ti = t2 >> 9, g = t2 & 511;
        int ct = ct_ti >> 2, ti = ct_ti & 3;
        int n = g >> 2;
        int h = ct * 128 + n;
        int qq = (g & 3) ^ ((n >> 1) & 3);
        int kb = ti * 32 + qq * 8;
        ushort8 o;
        #pragma unroll
        for (int e = 0; e < 8; e++) {
            int k = kb + e;
            int p = k >> 1;
            float v = (k & 1) ? -2.f * Ci[h * 64 + p] : 2.f * Cr[h * 64 + p];
            o[e] = f2bf(v);
        }
        *(ushort8*)&CeffT[t2 * 8] = o;
    }
}

// -------------------------------------------- GEMM 1 + fused local scan ----
// (round-2 structure: LDS-staged A and B, coalesced loads, 32-wide K-steps;
//  correction loop uses in-register dA power recurrence instead of dApow loads)
__global__ __launch_bounds__(256) void gemm1s(const float* __restrict__ u,
                                              const ushort_t* __restrict__ W1T,
                                              const float* __restrict__ params,
                                              const float* __restrict__ dApow,
                                              float* __restrict__ hloc,
                                              float* __restrict__ endbuf) {
    __shared__ float bus[128 * 128];            // 64 KB; aliases staging below
    ushort_t* As = (ushort_t*)bus;              // [128][40] bf16
    ushort_t* Bs = As + 128 * 40;               // [128][40] bf16
    int tid = threadIdx.x;
    int wave = tid >> 6, lane = tid & 63;
    int q = lane >> 4, mn = lane & 15;
    size_t row0 = (size_t)blockIdx.x * 128;
    int r = tid >> 1, half = tid & 1;

    floatx4 acc[2][8] = {};

    for (int kk = 0; kk < 1024; kk += 32) {
        __syncthreads();
        {
            const float4* up = (const float4*)(u + (row0 + r) * 1024 + kk + half * 16);
            float4 f0 = up[0], f1 = up[1], f2 = up[2], f3 = up[3];
            ushort8 t0, t1;
            t0[0] = f2bf(f0.x); t0[1] = f2bf(f0.y); t0[2] = f2bf(f0.z); t0[3] = f2bf(f0.w);
            t0[4] = f2bf(f1.x); t0[5] = f2bf(f1.y); t0[6] = f2bf(f1.z); t0[7] = f2bf(f1.w);
            t1[0] = f2bf(f2.x); t1[1] = f2bf(f2.y); t1[2] = f2bf(f2.z); t1[3] = f2bf(f2.w);
            t1[4] = f2bf(f3.x); t1[5] = f2bf(f3.y); t1[6] = f2bf(f3.z); t1[7] = f2bf(f3.w);
            ushort8* dst = (ushort8*)&As[r * 40 + half * 16];
            dst[0] = t0; dst[1] = t1;
            const ushort8* wp = (const ushort8*)(W1T + r * 1024 + kk + half * 16);
            ushort8* db = (ushort8*)&Bs[r * 40 + half * 16];
            db[0] = wp[0]; db[1] = wp[1];
        }
        __syncthreads();
        s8v a0 = *(const s8v*)&As[(wave * 32 + mn) * 40 + q * 8];
        s8v a1 = *(const s8v*)&As[(wave * 32 + 16 + mn) * 40 + q * 8];
        #pragma unroll
        for (int j = 0; j < 8; j++) {
            s8v bf = *(const s8v*)&Bs[(j * 16 + mn) * 40 + q * 8];
            acc[0][j] = MFMA16(a0, bf, acc[0][j]);
            acc[1][j] = MFMA16(a1, bf, acc[1][j]);
        }
    }
    __syncthreads();   // staging LDS dead; safe to overwrite with Bu tile
    #pragma unroll
    for (int i = 0; i < 2; i++)
        #pragma unroll
        for (int j = 0; j < 8; j++)
            #pragma unroll
            for (int reg = 0; reg < 4; reg++) {
                int row = wave * 32 + i * 16 + q * 4 + reg;
                bus[row * 128 + j * 16 + mn] = acc[i][j][reg];
            }
    __syncthreads();

    // --- wave-local scan over this wave's 32 rows (zero initial state) ---
    float dAr = params[lane], dAi = params[64 + lane];
    float hr = 0.f, hi = 0.f;
    int base = wave * 32 * 128 + 2 * lane;
    #pragma unroll 8
    for (int t = 0; t < 32; t++) {
        float2 v = *(float2*)&bus[base + t * 128];
        float nhr = fmaf(dAr, hr, fmaf(-dAi, hi, v.x));
        float nhi = fmaf(dAr, hi, fmaf(dAi, hr, v.y));
        hr = nhr; hi = nhi;
        *(float2*)&bus[base + t * 128] = make_float2(hr, hi);
    }
    __syncthreads();

    // --- cross-wave carry: c_w = sum_{w'<w} dA^(32*(w-1-w')) * e_{w'} ---
    float a32r = dApow[32 * 128 + 2 * lane], a32i = dApow[32 * 128 + 2 * lane + 1];
    float cr = 0.f, ci = 0.f;
    for (int w2 = 0; w2 < wave; w2++) {
        float2 e = *(float2*)&bus[(w2 * 32 + 31) * 128 + 2 * lane];
        float tr = fmaf(a32r, cr, fmaf(-a32i, ci, e.x));
        float ti = fmaf(a32r, ci, fmaf(a32i, cr, e.y));
        cr = tr; ci = ti;
    }

    // --- correction + coalesced write: h[l] = h_w[t] + dA^(t+1)*c_w ---
    // dA^(t+1) via in-register recurrence (bit-identical to dApow table).
    float* gbase = hloc + (row0 + wave * 32) * 128 + 2 * lane;
    float lr = 0.f, li = 0.f;
    float pr = dAr, pi = dAi;   // dA^1
    #pragma unroll 8
    for (int t = 0; t < 32; t++) {
        float2 v = *(float2*)&bus[base + t * 128];
        float orr = v.x + pr * cr - pi * ci;
        float oi  = v.y + pr * ci + pi * cr;
        *(float2*)(gbase + (size_t)t * 128) = make_float2(orr, oi);
        lr = orr; li = oi;
        float npr = pr * dAr - pi * dAi;
        float npi = pr * dAi + pi * dAr;
        pr = npr; pi = npi;
    }
    if (wave == 3) {   // chunk end state (corrected h at local row 127)
        float* e = endbuf + (size_t)blockIdx.x * 128 + 2 * lane;
        e[0] = lr; e[1] = li;
    }
}

// --------------------------------------------------------- carry scan ----
// carry[c] = state entering chunk c; carry[0] = h0 (folds initial state).
__global__ void scan_carry(const float* __restrict__ endbuf,
                           const float* __restrict__ dApow,
                           const float* __restrict__ h0r,
                           const float* __restrict__ h0i,
                           float* __restrict__ carry) {
    int t = blockIdx.x * 64 + threadIdx.x;  // 512 = 8*64
    int b = t >> 6, p = t & 63;
    float aSr = dApow[S_CH * 128 + 2 * p], aSi = dApow[S_CH * 128 + 2 * p + 1];
    float cr = h0r[b * 64 + p], ci = h0i[b * 64 + p];
    for (int c = 0; c < NC; c++) {
        float* dst = carry + ((size_t)b * NC + c) * 128 + 2 * p;
        dst[0] = cr; dst[1] = ci;
        const float* e = endbuf + ((size_t)b * NC + c) * 128 + 2 * p;
        float er = e[0], ei = e[1];
        float nr = fmaf(aSr, cr, fmaf(-aSi, ci, er));
        float ni = fmaf(aSr, ci, fmaf(aSi, cr, ei));
        cr = nr; ci = ni;
    }
}

// ------------------------------------------------------------- GEMM 2 ----
// A (hfix) built in registers once: hloc + dA^(r+1)*carry -> bf16, held in
// 8 s8v across the ct loop. B (CeffT) staged per-ct-tile (32 KB) swizzled
// via global_load_lds -> conflict-free ds_read_b128, 3 blocks/CU.
__global__ __launch_bounds__(256) void gemm2(const float* __restrict__ hloc,
                                             const ushort_t* __restrict__ CeffT,
                                             const float* __restrict__ u,
                                             const float* __restrict__ D,
                                             const float* __restrict__ dApow,
                                             const float* __restrict__ carry,
                                             float* __restrict__ y,
                                             float* __restrict__ out_hlast) {
    __shared__ ushort_t Blds[16384];   // 32 KB: one column-tile (128 h x 128 k)
    int tid = threadIdx.x;
    int wave = tid >> 6, lane = tid & 63;
    int q = lane >> 4, mn = lane & 15;
    int swz = q ^ ((mn >> 1) & 3);
    size_t row0 = (size_t)blockIdx.x * 128;
    int b = blockIdx.x >> 6;          // batch
    int c = blockIdx.x & 63;          // chunk (S_CH==128==block rows)

    // ---- A fragments with fixup, in registers ----
    u32x4 A[2][4];
    #pragma unroll
    for (int i = 0; i < 2; i++) {
        int r_i = wave * 32 + i * 16 + mn;
        int kp = r_i + 1;
        const float* hrow = hloc + (row0 + r_i) * 128;
        const float* prow = dApow + (size_t)kp * 128;
        const float* crow = carry + ((size_t)b * NC + c) * 128;
        bool last = (c == NC - 1) && (r_i == 127);
        #pragma unroll
        for (int kt = 0; kt < 4; kt++) {
            int kb = kt * 32 + q * 8;
            float4 h0 = *(const float4*)(hrow + kb);
            float4 h1 = *(const float4*)(hrow + kb + 4);
            float4 p0 = *(const float4*)(prow + kb);
            float4 p1 = *(const float4*)(prow + kb + 4);
            float4 c0 = *(const float4*)(crow + kb);
            float4 c1 = *(const float4*)(crow + kb + 4);
            float f0 = h0.x + p0.x * c0.x - p0.y * c0.y;
            float f1 = h0.y + p0.x * c0.y + p0.y * c0.x;
            float f2 = h0.z + p0.z * c0.z - p0.w * c0.w;
            float f3 = h0.w + p0.z * c0.w + p0.w * c0.z;
            float f4 = h1.x + p1.x * c1.x - p1.y * c1.y;
            float f5 = h1.y + p1.x * c1.y + p1.y * c1.x;
            float f6 = h1.z + p1.z * c1.z - p1.w * c1.w;
            float f7 = h1.w + p1.z * c1.w + p1.w * c1.z;
            A[i][kt].u[0] = cvtpk(f0, f1); A[i][kt].u[1] = cvtpk(f2, f3);
            A[i][kt].u[2] = cvtpk(f4, f5); A[i][kt].u[3] = cvtpk(f6, f7);
            if (last) {
                int pb = kt * 16 + q * 4;
                out_hlast[b * 64 + pb]           = f0; out_hlast[512 + b * 64 + pb]     = f1;
                out_hlast[b * 64 + pb + 1]       = f2; out_hlast[512 + b * 64 + pb + 1] = f3;
                out_hlast[b * 64 + pb + 2]       = f4; out_hlast[512 + b * 64 + pb + 2] = f5;
                out_hlast[b * 64 + pb + 3]       = f6; out_hlast[512 + b * 64 + pb + 3] = f7;
            }
        }
    }

    for (int ct = 0; ct < 8; ct++) {
        if (ct) __syncthreads();          // readers of previous tile done
        {   // stage 32KB swizzled CeffT column-tile ct, linear copy
            const ushort_t* gsrc = CeffT + (size_t)ct * 16384 + wave * 512 + lane * 8;
            ushort_t* ldst = Blds + wave * 512;
            #pragma unroll
            for (int it = 0; it < 8; it++)
                gload_lds16(gsrc + it * 2048, ldst + it * 2048);
        }
        __syncthreads();                  // drain: tile ready
        floatx4 acc[2][8] = {};
        #pragma unroll
        for (int kt = 0; kt < 4; kt++) {
            int bofs = kt * 4096 + swz * 8;
            #pragma unroll
            for (int j = 0; j < 8; j++) {
                s8v bf = *(const s8v*)&Blds[bofs + (j * 16 + mn) * 32];
                acc[0][j] = MFMA16(A[0][kt].v, bf, acc[0][j]);
                acc[1][j] = MFMA16(A[1][kt].v, bf, acc[1][j]);
            }
        }
        float dv[8];
        #pragma unroll
        for (int j = 0; j < 8; j++) dv[j] = D[ct * 128 + j * 16 + mn];
        #pragma unroll
        for (int i = 0; i < 2; i++)
            #pragma unroll
            for (int j = 0; j < 8; j++) {
                int col = ct * 128 + j * 16 + mn;
                #pragma unroll
                for (int reg = 0; reg < 4; reg++) {
                    size_t row = row0 + wave * 32 + i * 16 + q * 4 + reg;
                    y[row * 1024 + col] = acc[i][j][reg] + dv[j] * u[row * 1024 + col];
                }
            }
    }
}

// -------------------------------------------------------------- launch ----
extern "C" void kernel_launch(void* const* d_in, const int* in_sizes, int n_in,
                              void* d_out, int out_size, void* d_ws, size_t ws_size,
                              hipStream_t stream) {
    const float* u      = (const float*)d_in[0];
    const float* h_r    = (const float*)d_in[1];
    const float* h_i    = (const float*)d_in[2];
    const float* A_real = (const float*)d_in[3];
    const float* A_imag = (const float*)d_in[4];
    const float* B_real = (const float*)d_in[5];
    const float* B_imag = (const float*)d_in[6];
    const float* C_real = (const float*)d_in[7];
    const float* C_imag = (const float*)d_in[8];
    const float* D      = (const float*)d_in[9];
    const float* inv_dt = (const float*)d_in[10];
    float* out = (float*)d_out;

    // workspace layout (floats from base; all 16B aligned)
    float* wsf       = (float*)d_ws;
    float* P_params  = wsf;                    // 256 used, reserve 1024
    float* P_dApow   = wsf + 1024;             // 129*128 = 16512, reserve 16640
    float* P_carry   = wsf + 1024 + 16640;     // 8*NC*128 = 65536
    float* P_end     = P_carry + 65536;        // 65536
    ushort_t* P_W1T  = (ushort_t*)(P_end + 65536);      // 128*1024 bf16 (linear)
    ushort_t* P_Ceff = P_W1T + 128 * 1024;              // 1024*128 bf16 (swizzled)
    float* P_Bu      = (float*)(P_Ceff + 1024 * 128);   // 65536*128 f32 (33.5MB)

    params_kernel<<<1, 64, 0, stream>>>(A_real, A_imag, inv_dt, P_params, P_dApow);
    build_w<<<576, 256, 0, stream>>>(B_real, B_imag, C_real, C_imag, P_params, P_W1T, P_Ceff);
    gemm1s<<<M_TOT / 128, 256, 0, stream>>>(u, P_W1T, P_params, P_dApow, P_Bu, P_end);
    scan_carry<<<8, 64, 0, stream>>>(P_end, P_dApow, h_r, h_i, P_carry);
    gemm2<<<M_TOT / 128, 256, 0, stream>>>(P_Bu, P_Ceff, u, D, P_dApow, P_carry,
                                           out, out + (size_t)M_TOT * H);
}

// Round 5
// 602.132 us; speedup vs baseline: 1.2501x; 1.2501x over previous
//
#include <hip/hip_runtime.h>

typedef unsigned short ushort_t;
typedef short s8v __attribute__((ext_vector_type(8)));
typedef unsigned short ushort8 __attribute__((ext_vector_type(8)));
typedef float floatx4 __attribute__((ext_vector_type(4)));

#define MFMA16(a, b, c) __builtin_amdgcn_mfma_f32_16x16x32_bf16((a), (b), (c), 0, 0, 0)

static constexpr int B_SZ = 8;
static constexpr int L = 8192;
static constexpr int H = 1024;
static constexpr int M_TOT = B_SZ * L;        // 65536 rows
static constexpr int S_CH = 128;              // chunk length == gemm1 row-tile
static constexpr int NC = L / S_CH;           // 64 chunks per batch

// round-to-nearest-even fp32 -> bf16 bits
__device__ inline ushort_t f2bf(float f) {
    union { float f; unsigned u; } v; v.f = f;
    unsigned r = v.u + 0x7fffu + ((v.u >> 16) & 1u);
    return (ushort_t)(r >> 16);
}

// packed f32x2 -> bf16x2 (RNE) in one instruction
__device__ inline unsigned cvtpk(float lo, float hi) {
    unsigned r;
    asm("v_cvt_pk_bf16_f32 %0, %1, %2" : "=v"(r) : "v"(lo), "v"(hi));
    return r;
}

typedef union { s8v v; unsigned u[4]; } u32x4;

// async global->LDS, 16B per lane; lds dest = wave-uniform base + lane*16
__device__ inline void gload_lds16(const void* g, void* l) {
    __builtin_amdgcn_global_load_lds(
        (const __attribute__((address_space(1))) void*)g,
        (__attribute__((address_space(3))) void*)l, 16, 0, 0);
}

// ---------------------------------------------------------------- params ----
// params[0..63]=dA_r [64..127]=dA_i [128..191]=s_r [192..255]=s_i
// dApow INTERLEAVED: dApow[k*128 + 2p] = Re(dA^k), [k*128+2p+1] = Im(dA^k)
__global__ void params_kernel(const float* __restrict__ A_real,
                              const float* __restrict__ A_imag,
                              const float* __restrict__ inv_dt,
                              float* __restrict__ params,
                              float* __restrict__ dApow) {
    int p = threadIdx.x;  // 64 threads
    float x = inv_dt[p];
    float dt = (x > 20.f) ? x : log1pf(expf(x));
    float ar = A_real[p], ai = A_imag[p];
    float dr = 1.f - 0.5f * dt * ar;
    float di = -0.5f * dt * ai;
    float inv = 1.f / fmaf(dr, dr, di * di);
    float nr = 1.f + 0.5f * dt * ar, ni = 0.5f * dt * ai;
    float dAr = (nr * dr + ni * di) * inv;
    float dAi = (ni * dr - nr * di) * inv;
    params[p]       = dAr;
    params[64 + p]  = dAi;
    params[128 + p] = dt * dr * inv;    // Re(dt/den)
    params[192 + p] = -dt * di * inv;   // Im(dt/den)
    float pr = 1.f, pi = 0.f;
    dApow[2 * p] = 1.f; dApow[2 * p + 1] = 0.f;
    for (int k = 1; k <= S_CH; k++) {
        float npr = pr * dAr - pi * dAi;
        float npi = pr * dAi + pi * dAr;
        pr = npr; pi = npi;
        dApow[k * 128 + 2 * p]     = pr;
        dApow[k * 128 + 2 * p + 1] = pi;
    }
}

// -------------------------------------------------- build bf16 weights ----
// W1T LINEAR rows: W1T[2p][k] = Re(s_p*B[p][k]), W1T[2p+1][k] = Im(...)
// CeffT SWIZZLED granules (16B): byte(granule) = tile*8192 + g*16,
//   g = n*4 + (q ^ ((n>>1)&3)), tile = ct*4 + k/32, n = h%128, ct = h/128.
//   Ceff[h][2p] = 2*Cr[h][p], Ceff[h][2p+1] = -2*Ci[h][p].
__global__ void build_w(const float* __restrict__ Br, const float* __restrict__ Bi,
                        const float* __restrict__ Cr, const float* __restrict__ Ci,
                        const float* __restrict__ params,
                        ushort_t* __restrict__ W1T, ushort_t* __restrict__ CeffT) {
    int t = blockIdx.x * 256 + threadIdx.x;   // 147456 threads
    if (t < 128 * 1024) {
        int n = t >> 10, k = t & 1023;
        int p = n >> 1;
        float sr = params[128 + p], si = params[192 + p];
        float br = Br[p * 1024 + k], bi = Bi[p * 1024 + k];
        float v = (n & 1) ? (sr * bi + si * br) : (sr * br - si * bi);
        W1T[t] = f2bf(v);
    } else {
        int t2 = t - 128 * 1024;              // 16384 granule-threads
        int ct_ti = t2 >> 9, g = t2 & 511;
        int ct = ct_ti >> 2, ti = ct_ti & 3;
        int n = g >> 2;
        int h = ct * 128 + n;
        int qq = (g & 3) ^ ((n >> 1) & 3);
        int kb = ti * 32 + qq * 8;
        ushort8 o;
        #pragma unroll
        for (int e = 0; e < 8; e++) {
            int k = kb + e;
            int p = k >> 1;
            float v = (k & 1) ? -2.f * Ci[h * 64 + p] : 2.f * Cr[h * 64 + p];
            o[e] = f2bf(v);
        }
        *(ushort8*)&CeffT[t2 * 8] = o;
    }
}

// -------------------------------------------- GEMM 1 + fused local scan ----
// (unchanged from round 4: measured <=163us; LDS-staged A and B, coalesced
//  loads, 32-wide K-steps, in-register dA power recurrence in correction)
__global__ __launch_bounds__(256) void gemm1s(const float* __restrict__ u,
                                              const ushort_t* __restrict__ W1T,
                                              const float* __restrict__ params,
                                              const float* __restrict__ dApow,
                                              float* __restrict__ hloc,
                                              float* __restrict__ endbuf) {
    __shared__ float bus[128 * 128];            // 64 KB; aliases staging below
    ushort_t* As = (ushort_t*)bus;              // [128][40] bf16
    ushort_t* Bs = As + 128 * 40;               // [128][40] bf16
    int tid = threadIdx.x;
    int wave = tid >> 6, lane = tid & 63;
    int q = lane >> 4, mn = lane & 15;
    size_t row0 = (size_t)blockIdx.x * 128;
    int r = tid >> 1, half = tid & 1;

    floatx4 acc[2][8] = {};

    for (int kk = 0; kk < 1024; kk += 32) {
        __syncthreads();
        {
            const float4* up = (const float4*)(u + (row0 + r) * 1024 + kk + half * 16);
            float4 f0 = up[0], f1 = up[1], f2 = up[2], f3 = up[3];
            ushort8 t0, t1;
            t0[0] = f2bf(f0.x); t0[1] = f2bf(f0.y); t0[2] = f2bf(f0.z); t0[3] = f2bf(f0.w);
            t0[4] = f2bf(f1.x); t0[5] = f2bf(f1.y); t0[6] = f2bf(f1.z); t0[7] = f2bf(f1.w);
            t1[0] = f2bf(f2.x); t1[1] = f2bf(f2.y); t1[2] = f2bf(f2.z); t1[3] = f2bf(f2.w);
            t1[4] = f2bf(f3.x); t1[5] = f2bf(f3.y); t1[6] = f2bf(f3.z); t1[7] = f2bf(f3.w);
            ushort8* dst = (ushort8*)&As[r * 40 + half * 16];
            dst[0] = t0; dst[1] = t1;
            const ushort8* wp = (const ushort8*)(W1T + r * 1024 + kk + half * 16);
            ushort8* db = (ushort8*)&Bs[r * 40 + half * 16];
            db[0] = wp[0]; db[1] = wp[1];
        }
        __syncthreads();
        s8v a0 = *(const s8v*)&As[(wave * 32 + mn) * 40 + q * 8];
        s8v a1 = *(const s8v*)&As[(wave * 32 + 16 + mn) * 40 + q * 8];
        #pragma unroll
        for (int j = 0; j < 8; j++) {
            s8v bf = *(const s8v*)&Bs[(j * 16 + mn) * 40 + q * 8];
            acc[0][j] = MFMA16(a0, bf, acc[0][j]);
            acc[1][j] = MFMA16(a1, bf, acc[1][j]);
        }
    }
    __syncthreads();   // staging LDS dead; safe to overwrite with Bu tile
    #pragma unroll
    for (int i = 0; i < 2; i++)
        #pragma unroll
        for (int j = 0; j < 8; j++)
            #pragma unroll
            for (int reg = 0; reg < 4; reg++) {
                int row = wave * 32 + i * 16 + q * 4 + reg;
                bus[row * 128 + j * 16 + mn] = acc[i][j][reg];
            }
    __syncthreads();

    // --- wave-local scan over this wave's 32 rows (zero initial state) ---
    float dAr = params[lane], dAi = params[64 + lane];
    float hr = 0.f, hi = 0.f;
    int base = wave * 32 * 128 + 2 * lane;
    #pragma unroll 8
    for (int t = 0; t < 32; t++) {
        float2 v = *(float2*)&bus[base + t * 128];
        float nhr = fmaf(dAr, hr, fmaf(-dAi, hi, v.x));
        float nhi = fmaf(dAr, hi, fmaf(dAi, hr, v.y));
        hr = nhr; hi = nhi;
        *(float2*)&bus[base + t * 128] = make_float2(hr, hi);
    }
    __syncthreads();

    // --- cross-wave carry: c_w = sum_{w'<w} dA^(32*(w-1-w')) * e_{w'} ---
    float a32r = dApow[32 * 128 + 2 * lane], a32i = dApow[32 * 128 + 2 * lane + 1];
    float cr = 0.f, ci = 0.f;
    for (int w2 = 0; w2 < wave; w2++) {
        float2 e = *(float2*)&bus[(w2 * 32 + 31) * 128 + 2 * lane];
        float tr = fmaf(a32r, cr, fmaf(-a32i, ci, e.x));
        float ti = fmaf(a32r, ci, fmaf(a32i, cr, e.y));
        cr = tr; ci = ti;
    }

    // --- correction + coalesced write: h[l] = h_w[t] + dA^(t+1)*c_w ---
    float* gbase = hloc + (row0 + wave * 32) * 128 + 2 * lane;
    float lr = 0.f, li = 0.f;
    float pr = dAr, pi = dAi;   // dA^1
    #pragma unroll 8
    for (int t = 0; t < 32; t++) {
        float2 v = *(float2*)&bus[base + t * 128];
        float orr = v.x + pr * cr - pi * ci;
        float oi  = v.y + pr * ci + pi * cr;
        *(float2*)(gbase + (size_t)t * 128) = make_float2(orr, oi);
        lr = orr; li = oi;
        float npr = pr * dAr - pi * dAi;
        float npi = pr * dAi + pi * dAr;
        pr = npr; pi = npi;
    }
    if (wave == 3) {   // chunk end state (corrected h at local row 127)
        float* e = endbuf + (size_t)blockIdx.x * 128 + 2 * lane;
        e[0] = lr; e[1] = li;
    }
}

// --------------------------------------------------------- carry scan ----
// carry[c] = state entering chunk c; carry[0] = h0 (folds initial state).
// Batch-loads chunk ends (independent) then runs the serial chain in-reg:
// 2 latency round-trips instead of 64 dependent ones.
__global__ void scan_carry(const float* __restrict__ endbuf,
                           const float* __restrict__ dApow,
                           const float* __restrict__ h0r,
                           const float* __restrict__ h0i,
                           float* __restrict__ carry) {
    int t = blockIdx.x * 64 + threadIdx.x;  // 512 = 8*64
    int b = t >> 6, p = t & 63;
    float aSr = dApow[S_CH * 128 + 2 * p], aSi = dApow[S_CH * 128 + 2 * p + 1];
    float cr = h0r[b * 64 + p], ci = h0i[b * 64 + p];
    #pragma unroll
    for (int half = 0; half < 2; half++) {
        float2 e[32];
        #pragma unroll
        for (int c = 0; c < 32; c++)
            e[c] = *(const float2*)(endbuf + ((size_t)b * NC + half * 32 + c) * 128 + 2 * p);
        #pragma unroll
        for (int c = 0; c < 32; c++) {
            int cc = half * 32 + c;
            *(float2*)(carry + ((size_t)b * NC + cc) * 128 + 2 * p) = make_float2(cr, ci);
            float nr = fmaf(aSr, cr, fmaf(-aSi, ci, e[c].x));
            float ni = fmaf(aSr, ci, fmaf(aSi, cr, e[c].y));
            cr = nr; ci = ni;
        }
    }
}

// --------------------------------------------- GEMM 2, transposed output ----
// y^T tiles: D = mfma(Ceff_frag, hfix_frag) so D-row (q*4+reg) indexes h and
// D-col (mn) indexes seq -> each thread owns 4 CONSECUTIVE h -> float4 u/y.
// 64-row blocks (grid 1024 = 4 blocks/CU, 32KB LDS). hfix B-frags built once
// in registers (hloc + dA^(l%S+1)*carry, cvt_pk). CeffT staged per-ct via
// global_load_lds with the verified conflict-free swizzle. Emits h_last.
__global__ __launch_bounds__(256, 4) void gemm2t(const float* __restrict__ hloc,
                                                 const ushort_t* __restrict__ CeffT,
                                                 const float* __restrict__ u,
                                                 const float* __restrict__ D,
                                                 const float* __restrict__ dApow,
                                                 const float* __restrict__ carry,
                                                 float* __restrict__ y,
                                                 float* __restrict__ out_hlast) {
    __shared__ ushort_t Blds[16384];   // 32 KB: one column-tile (128 h x 128 k)
    int tid = threadIdx.x;
    int w = tid >> 6, lane = tid & 63;
    int q = lane >> 4, mn = lane & 15;
    int swz = q ^ ((mn >> 1) & 3);
    size_t row0 = (size_t)blockIdx.x * 64;
    int b = (int)(row0 >> 13);            // batch
    int l0 = (int)(row0 & (L - 1));
    int c = l0 >> 7;                      // chunk (S_CH = 128; 64 | 128)

    int seq = w * 16 + mn;                // local row owned by this lane
    int l = l0 + seq;
    int kp = (l & (S_CH - 1)) + 1;
    const float* hrow = hloc + (row0 + seq) * 128;
    const float* prow = dApow + (size_t)kp * 128;
    const float* crow = carry + ((size_t)b * NC + c) * 128;
    bool last = (l == L - 1);

    // ---- hfix B-fragments (one seq row per lane, k-quarter q), in regs ----
    u32x4 Bf[4];
    #pragma unroll
    for (int kt = 0; kt < 4; kt++) {
        int kb = kt * 32 + q * 8;
        float4 h0 = *(const float4*)(hrow + kb);
        float4 h1 = *(const float4*)(hrow + kb + 4);
        float4 p0 = *(const float4*)(prow + kb);
        float4 p1 = *(const float4*)(prow + kb + 4);
        float4 c0 = *(const float4*)(crow + kb);
        float4 c1 = *(const float4*)(crow + kb + 4);
        float f0 = h0.x + p0.x * c0.x - p0.y * c0.y;
        float f1 = h0.y + p0.x * c0.y + p0.y * c0.x;
        float f2 = h0.z + p0.z * c0.z - p0.w * c0.w;
        float f3 = h0.w + p0.z * c0.w + p0.w * c0.z;
        float f4 = h1.x + p1.x * c1.x - p1.y * c1.y;
        float f5 = h1.y + p1.x * c1.y + p1.y * c1.x;
        float f6 = h1.z + p1.z * c1.z - p1.w * c1.w;
        float f7 = h1.w + p1.z * c1.w + p1.w * c1.z;
        Bf[kt].u[0] = cvtpk(f0, f1); Bf[kt].u[1] = cvtpk(f2, f3);
        Bf[kt].u[2] = cvtpk(f4, f5); Bf[kt].u[3] = cvtpk(f6, f7);
        if (last) {
            int pb = kb >> 1;
            out_hlast[b * 64 + pb]     = f0; out_hlast[512 + b * 64 + pb]     = f1;
            out_hlast[b * 64 + pb + 1] = f2; out_hlast[512 + b * 64 + pb + 1] = f3;
            out_hlast[b * 64 + pb + 2] = f4; out_hlast[512 + b * 64 + pb + 2] = f5;
            out_hlast[b * 64 + pb + 3] = f6; out_hlast[512 + b * 64 + pb + 3] = f7;
        }
    }

    const float* urow = u + (row0 + seq) * 1024;
    float* yrow = y + (row0 + seq) * 1024;

    for (int ct = 0; ct < 8; ct++) {
        if (ct) __syncthreads();          // readers of previous tile done
        {   // stage 32KB swizzled CeffT column-tile ct
            const ushort_t* gsrc = CeffT + (size_t)ct * 16384 + w * 512 + lane * 8;
            ushort_t* ldst = Blds + w * 512;
            #pragma unroll
            for (int it = 0; it < 8; it++)
                gload_lds16(gsrc + it * 2048, ldst + it * 2048);
        }
        __syncthreads();                  // tile ready
        floatx4 acc[8] = {};
        #pragma unroll
        for (int kt = 0; kt < 4; kt++) {
            int bofs = kt * 4096 + swz * 8;
            #pragma unroll
            for (int j = 0; j < 8; j++) {
                s8v af = *(const s8v*)&Blds[bofs + (j * 16 + mn) * 32];
                acc[j] = MFMA16(af, Bf[kt].v, acc[j]);
            }
        }
        #pragma unroll
        for (int j = 0; j < 8; j++) {
            int h = ct * 128 + j * 16 + q * 4;
            float4 uv = *(const float4*)(urow + h);
            float4 dv = *(const float4*)(D + h);
            float4 o;
            o.x = acc[j][0] + dv.x * uv.x;
            o.y = acc[j][1] + dv.y * uv.y;
            o.z = acc[j][2] + dv.z * uv.z;
            o.w = acc[j][3] + dv.w * uv.w;
            *(float4*)(yrow + h) = o;
        }
    }
}

// -------------------------------------------------------------- launch ----
extern "C" void kernel_launch(void* const* d_in, const int* in_sizes, int n_in,
                              void* d_out, int out_size, void* d_ws, size_t ws_size,
                              hipStream_t stream) {
    const float* u      = (const float*)d_in[0];
    const float* h_r    = (const float*)d_in[1];
    const float* h_i    = (const float*)d_in[2];
    const float* A_real = (const float*)d_in[3];
    const float* A_imag = (const float*)d_in[4];
    const float* B_real = (const float*)d_in[5];
    const float* B_imag = (const float*)d_in[6];
    const float* C_real = (const float*)d_in[7];
    const float* C_imag = (const float*)d_in[8];
    const float* D      = (const float*)d_in[9];
    const float* inv_dt = (const float*)d_in[10];
    float* out = (float*)d_out;

    // workspace layout (floats from base; all 16B aligned)
    float* wsf       = (float*)d_ws;
    float* P_params  = wsf;                    // 256 used, reserve 1024
    float* P_dApow   = wsf + 1024;             // 129*128 = 16512, reserve 16640
    float* P_carry   = wsf + 1024 + 16640;     // 8*NC*128 = 65536
    float* P_end     = P_carry + 65536;        // 65536
    ushort_t* P_W1T  = (ushort_t*)(P_end + 65536);      // 128*1024 bf16 (linear)
    ushort_t* P_Ceff = P_W1T + 128 * 1024;              // 1024*128 bf16 (swizzled)
    float* P_Bu      = (float*)(P_Ceff + 1024 * 128);   // 65536*128 f32 (33.5MB)

    params_kernel<<<1, 64, 0, stream>>>(A_real, A_imag, inv_dt, P_params, P_dApow);
    build_w<<<576, 256, 0, stream>>>(B_real, B_imag, C_real, C_imag, P_params, P_W1T, P_Ceff);
    gemm1s<<<M_TOT / 128, 256, 0, stream>>>(u, P_W1T, P_params, P_dApow, P_Bu, P_end);
    scan_carry<<<8, 64, 0, stream>>>(P_end, P_dApow, h_r, h_i, P_carry);
    gemm2t<<<M_TOT / 64, 256, 0, stream>>>(P_Bu, P_Ceff, u, D, P_dApow, P_carry,
                                           out, out + (size_t)M_TOT * H);
}

// Round 6
// 601.534 us; speedup vs baseline: 1.2513x; 1.0010x over previous
//
#include <hip/hip_runtime.h>

typedef unsigned short ushort_t;
typedef short s8v __attribute__((ext_vector_type(8)));
typedef unsigned short ushort8 __attribute__((ext_vector_type(8)));
typedef float floatx4 __attribute__((ext_vector_type(4)));

#define MFMA16(a, b, c) __builtin_amdgcn_mfma_f32_16x16x32_bf16((a), (b), (c), 0, 0, 0)

static constexpr int B_SZ = 8;
static constexpr int L = 8192;
static constexpr int H = 1024;
static constexpr int M_TOT = B_SZ * L;        // 65536 rows
static constexpr int S_CH = 128;              // chunk length == gemm1 row-tile
static constexpr int NC = L / S_CH;           // 64 chunks per batch

// round-to-nearest-even fp32 -> bf16 bits
__device__ inline ushort_t f2bf(float f) {
    union { float f; unsigned u; } v; v.f = f;
    unsigned r = v.u + 0x7fffu + ((v.u >> 16) & 1u);
    return (ushort_t)(r >> 16);
}

// packed f32x2 -> bf16x2 (RNE) in one instruction
__device__ inline unsigned cvtpk(float lo, float hi) {
    unsigned r;
    asm("v_cvt_pk_bf16_f32 %0, %1, %2" : "=v"(r) : "v"(lo), "v"(hi));
    return r;
}

typedef union { s8v v; unsigned u[4]; } u32x4;

// async global->LDS, 16B per lane; lds dest = wave-uniform base + lane*16
__device__ inline void gload_lds16(const void* g, void* l) {
    __builtin_amdgcn_global_load_lds(
        (const __attribute__((address_space(1))) void*)g,
        (__attribute__((address_space(3))) void*)l, 16, 0, 0);
}

// ---------------------------------------------------------------- params ----
// params[0..63]=dA_r [64..127]=dA_i [128..191]=s_r [192..255]=s_i
// dApow INTERLEAVED: dApow[k*128 + 2p] = Re(dA^k), [k*128+2p+1] = Im(dA^k)
__global__ void params_kernel(const float* __restrict__ A_real,
                              const float* __restrict__ A_imag,
                              const float* __restrict__ inv_dt,
                              float* __restrict__ params,
                              float* __restrict__ dApow) {
    int p = threadIdx.x;  // 64 threads
    float x = inv_dt[p];
    float dt = (x > 20.f) ? x : log1pf(expf(x));
    float ar = A_real[p], ai = A_imag[p];
    float dr = 1.f - 0.5f * dt * ar;
    float di = -0.5f * dt * ai;
    float inv = 1.f / fmaf(dr, dr, di * di);
    float nr = 1.f + 0.5f * dt * ar, ni = 0.5f * dt * ai;
    float dAr = (nr * dr + ni * di) * inv;
    float dAi = (ni * dr - nr * di) * inv;
    params[p]       = dAr;
    params[64 + p]  = dAi;
    params[128 + p] = dt * dr * inv;    // Re(dt/den)
    params[192 + p] = -dt * di * inv;   // Im(dt/den)
    float pr = 1.f, pi = 0.f;
    dApow[2 * p] = 1.f; dApow[2 * p + 1] = 0.f;
    for (int k = 1; k <= S_CH; k++) {
        float npr = pr * dAr - pi * dAi;
        float npi = pr * dAi + pi * dAr;
        pr = npr; pi = npi;
        dApow[k * 128 + 2 * p]     = pr;
        dApow[k * 128 + 2 * p + 1] = pi;
    }
}

// -------------------------------------------------- build bf16 weights ----
// W1T LINEAR rows: W1T[2p][k] = Re(s_p*B[p][k]), W1T[2p+1][k] = Im(...)
// CeffT SWIZZLED granules (16B): byte(granule) = tile*8192 + g*16,
//   g = n*4 + (q ^ ((n>>1)&3)), tile = ct*4 + k/32, n = h%128, ct = h/128.
//   Ceff[h][2p] = 2*Cr[h][p], Ceff[h][2p+1] = -2*Ci[h][p].
__global__ void build_w(const float* __restrict__ Br, const float* __restrict__ Bi,
                        const float* __restrict__ Cr, const float* __restrict__ Ci,
                        const float* __restrict__ params,
                        ushort_t* __restrict__ W1T, ushort_t* __restrict__ CeffT) {
    int t = blockIdx.x * 256 + threadIdx.x;   // 147456 threads
    if (t < 128 * 1024) {
        int n = t >> 10, k = t & 1023;
        int p = n >> 1;
        float sr = params[128 + p], si = params[192 + p];
        float br = Br[p * 1024 + k], bi = Bi[p * 1024 + k];
        float v = (n & 1) ? (sr * bi + si * br) : (sr * br - si * bi);
        W1T[t] = f2bf(v);
    } else {
        int t2 = t - 128 * 1024;              // 16384 granule-threads
        int ct_ti = t2 >> 9, g = t2 & 511;
        int ct = ct_ti >> 2, ti = ct_ti & 3;
        int n = g >> 2;
        int h = ct * 128 + n;
        int qq = (g & 3) ^ ((n >> 1) & 3);
        int kb = ti * 32 + qq * 8;
        ushort8 o;
        #pragma unroll
        for (int e = 0; e < 8; e++) {
            int k = kb + e;
            int p = k >> 1;
            float v = (k & 1) ? -2.f * Ci[h * 64 + p] : 2.f * Cr[h * 64 + p];
            o[e] = f2bf(v);
        }
        *(ushort8*)&CeffT[t2 * 8] = o;
    }
}

// -------------------------------------------- GEMM 1 + fused local scan ----
// Round-5 structure; ONLY change: staging f32->bf16 conversion now uses
// v_cvt_pk_bf16_f32 (8 instrs) instead of 16 scalar f2bf (~64 VALU instrs).
__global__ __launch_bounds__(256) void gemm1s(const float* __restrict__ u,
                                              const ushort_t* __restrict__ W1T,
                                              const float* __restrict__ params,
                                              const float* __restrict__ dApow,
                                              float* __restrict__ hloc,
                                              float* __restrict__ endbuf) {
    __shared__ float bus[128 * 128];            // 64 KB; aliases staging below
    ushort_t* As = (ushort_t*)bus;              // [128][40] bf16
    ushort_t* Bs = As + 128 * 40;               // [128][40] bf16
    int tid = threadIdx.x;
    int wave = tid >> 6, lane = tid & 63;
    int q = lane >> 4, mn = lane & 15;
    size_t row0 = (size_t)blockIdx.x * 128;
    int r = tid >> 1, half = tid & 1;

    floatx4 acc[2][8] = {};

    for (int kk = 0; kk < 1024; kk += 32) {
        __syncthreads();
        {
            const float4* up = (const float4*)(u + (row0 + r) * 1024 + kk + half * 16);
            float4 f0 = up[0], f1 = up[1], f2 = up[2], f3 = up[3];
            u32x4 t0, t1;
            t0.u[0] = cvtpk(f0.x, f0.y); t0.u[1] = cvtpk(f0.z, f0.w);
            t0.u[2] = cvtpk(f1.x, f1.y); t0.u[3] = cvtpk(f1.z, f1.w);
            t1.u[0] = cvtpk(f2.x, f2.y); t1.u[1] = cvtpk(f2.z, f2.w);
            t1.u[2] = cvtpk(f3.x, f3.y); t1.u[3] = cvtpk(f3.z, f3.w);
            s8v* dst = (s8v*)&As[r * 40 + half * 16];
            dst[0] = t0.v; dst[1] = t1.v;
            const ushort8* wp = (const ushort8*)(W1T + r * 1024 + kk + half * 16);
            ushort8* db = (ushort8*)&Bs[r * 40 + half * 16];
            db[0] = wp[0]; db[1] = wp[1];
        }
        __syncthreads();
        s8v a0 = *(const s8v*)&As[(wave * 32 + mn) * 40 + q * 8];
        s8v a1 = *(const s8v*)&As[(wave * 32 + 16 + mn) * 40 + q * 8];
        #pragma unroll
        for (int j = 0; j < 8; j++) {
            s8v bf = *(const s8v*)&Bs[(j * 16 + mn) * 40 + q * 8];
            acc[0][j] = MFMA16(a0, bf, acc[0][j]);
            acc[1][j] = MFMA16(a1, bf, acc[1][j]);
        }
    }
    __syncthreads();   // staging LDS dead; safe to overwrite with Bu tile
    #pragma unroll
    for (int i = 0; i < 2; i++)
        #pragma unroll
        for (int j = 0; j < 8; j++)
            #pragma unroll
            for (int reg = 0; reg < 4; reg++) {
                int row = wave * 32 + i * 16 + q * 4 + reg;
                bus[row * 128 + j * 16 + mn] = acc[i][j][reg];
            }
    __syncthreads();

    // --- wave-local scan over this wave's 32 rows (zero initial state) ---
    float dAr = params[lane], dAi = params[64 + lane];
    float hr = 0.f, hi = 0.f;
    int base = wave * 32 * 128 + 2 * lane;
    #pragma unroll 8
    for (int t = 0; t < 32; t++) {
        float2 v = *(float2*)&bus[base + t * 128];
        float nhr = fmaf(dAr, hr, fmaf(-dAi, hi, v.x));
        float nhi = fmaf(dAr, hi, fmaf(dAi, hr, v.y));
        hr = nhr; hi = nhi;
        *(float2*)&bus[base + t * 128] = make_float2(hr, hi);
    }
    __syncthreads();

    // --- cross-wave carry: c_w = sum_{w'<w} dA^(32*(w-1-w')) * e_{w'} ---
    float a32r = dApow[32 * 128 + 2 * lane], a32i = dApow[32 * 128 + 2 * lane + 1];
    float cr = 0.f, ci = 0.f;
    for (int w2 = 0; w2 < wave; w2++) {
        float2 e = *(float2*)&bus[(w2 * 32 + 31) * 128 + 2 * lane];
        float tr = fmaf(a32r, cr, fmaf(-a32i, ci, e.x));
        float ti = fmaf(a32r, ci, fmaf(a32i, cr, e.y));
        cr = tr; ci = ti;
    }

    // --- correction + coalesced write: h[l] = h_w[t] + dA^(t+1)*c_w ---
    float* gbase = hloc + (row0 + wave * 32) * 128 + 2 * lane;
    float lr = 0.f, li = 0.f;
    float pr = dAr, pi = dAi;   // dA^1
    #pragma unroll 8
    for (int t = 0; t < 32; t++) {
        float2 v = *(float2*)&bus[base + t * 128];
        float orr = v.x + pr * cr - pi * ci;
        float oi  = v.y + pr * ci + pi * cr;
        *(float2*)(gbase + (size_t)t * 128) = make_float2(orr, oi);
        lr = orr; li = oi;
        float npr = pr * dAr - pi * dAi;
        float npi = pr * dAi + pi * dAr;
        pr = npr; pi = npi;
    }
    if (wave == 3) {   // chunk end state (corrected h at local row 127)
        float* e = endbuf + (size_t)blockIdx.x * 128 + 2 * lane;
        e[0] = lr; e[1] = li;
    }
}

// --------------------------------------------------------- carry scan ----
// carry[c] = state entering chunk c; carry[0] = h0 (folds initial state).
// Batch-loads chunk ends (independent) then runs the serial chain in-reg.
__global__ void scan_carry(const float* __restrict__ endbuf,
                           const float* __restrict__ dApow,
                           const float* __restrict__ h0r,
                           const float* __restrict__ h0i,
                           float* __restrict__ carry) {
    int t = blockIdx.x * 64 + threadIdx.x;  // 512 = 8*64
    int b = t >> 6, p = t & 63;
    float aSr = dApow[S_CH * 128 + 2 * p], aSi = dApow[S_CH * 128 + 2 * p + 1];
    float cr = h0r[b * 64 + p], ci = h0i[b * 64 + p];
    #pragma unroll
    for (int half = 0; half < 2; half++) {
        float2 e[32];
        #pragma unroll
        for (int c = 0; c < 32; c++)
            e[c] = *(const float2*)(endbuf + ((size_t)b * NC + half * 32 + c) * 128 + 2 * p);
        #pragma unroll
        for (int c = 0; c < 32; c++) {
            int cc = half * 32 + c;
            *(float2*)(carry + ((size_t)b * NC + cc) * 128 + 2 * p) = make_float2(cr, ci);
            float nr = fmaf(aSr, cr, fmaf(-aSi, ci, e[c].x));
            float ni = fmaf(aSr, ci, fmaf(aSi, cr, e[c].y));
            cr = nr; ci = ni;
        }
    }
}

// --------------------------------------------- GEMM 2, transposed output ----
// (unchanged from round 5)
__global__ __launch_bounds__(256, 4) void gemm2t(const float* __restrict__ hloc,
                                                 const ushort_t* __restrict__ CeffT,
                                                 const float* __restrict__ u,
                                                 const float* __restrict__ D,
                                                 const float* __restrict__ dApow,
                                                 const float* __restrict__ carry,
                                                 float* __restrict__ y,
                                                 float* __restrict__ out_hlast) {
    __shared__ ushort_t Blds[16384];   // 32 KB: one column-tile (128 h x 128 k)
    int tid = threadIdx.x;
    int w = tid >> 6, lane = tid & 63;
    int q = lane >> 4, mn = lane & 15;
    int swz = q ^ ((mn >> 1) & 3);
    size_t row0 = (size_t)blockIdx.x * 64;
    int b = (int)(row0 >> 13);            // batch
    int l0 = (int)(row0 & (L - 1));
    int c = l0 >> 7;                      // chunk (S_CH = 128; 64 | 128)

    int seq = w * 16 + mn;                // local row owned by this lane
    int l = l0 + seq;
    int kp = (l & (S_CH - 1)) + 1;
    const float* hrow = hloc + (row0 + seq) * 128;
    const float* prow = dApow + (size_t)kp * 128;
    const float* crow = carry + ((size_t)b * NC + c) * 128;
    bool last = (l == L - 1);

    // ---- hfix B-fragments (one seq row per lane, k-quarter q), in regs ----
    u32x4 Bf[4];
    #pragma unroll
    for (int kt = 0; kt < 4; kt++) {
        int kb = kt * 32 + q * 8;
        float4 h0 = *(const float4*)(hrow + kb);
        float4 h1 = *(const float4*)(hrow + kb + 4);
        float4 p0 = *(const float4*)(prow + kb);
        float4 p1 = *(const float4*)(prow + kb + 4);
        float4 c0 = *(const float4*)(crow + kb);
        float4 c1 = *(const float4*)(crow + kb + 4);
        float f0 = h0.x + p0.x * c0.x - p0.y * c0.y;
        float f1 = h0.y + p0.x * c0.y + p0.y * c0.x;
        float f2 = h0.z + p0.z * c0.z - p0.w * c0.w;
        float f3 = h0.w + p0.z * c0.w + p0.w * c0.z;
        float f4 = h1.x + p1.x * c1.x - p1.y * c1.y;
        float f5 = h1.y + p1.x * c1.y + p1.y * c1.x;
        float f6 = h1.z + p1.z * c1.z - p1.w * c1.w;
        float f7 = h1.w + p1.z * c1.w + p1.w * c1.z;
        Bf[kt].u[0] = cvtpk(f0, f1); Bf[kt].u[1] = cvtpk(f2, f3);
        Bf[kt].u[2] = cvtpk(f4, f5); Bf[kt].u[3] = cvtpk(f6, f7);
        if (last) {
            int pb = kb >> 1;
            out_hlast[b * 64 + pb]     = f0; out_hlast[512 + b * 64 + pb]     = f1;
            out_hlast[b * 64 + pb + 1] = f2; out_hlast[512 + b * 64 + pb + 1] = f3;
            out_hlast[b * 64 + pb + 2] = f4; out_hlast[512 + b * 64 + pb + 2] = f5;
            out_hlast[b * 64 + pb + 3] = f6; out_hlast[512 + b * 64 + pb + 3] = f7;
        }
    }

    const float* urow = u + (row0 + seq) * 1024;
    float* yrow = y + (row0 + seq) * 1024;

    for (int ct = 0; ct < 8; ct++) {
        if (ct) __syncthreads();          // readers of previous tile done
        {   // stage 32KB swizzled CeffT column-tile ct
            const ushort_t* gsrc = CeffT + (size_t)ct * 16384 + w * 512 + lane * 8;
            ushort_t* ldst = Blds + w * 512;
            #pragma unroll
            for (int it = 0; it < 8; it++)
                gload_lds16(gsrc + it * 2048, ldst + it * 2048);
        }
        __syncthreads();                  // tile ready
        floatx4 acc[8] = {};
        #pragma unroll
        for (int kt = 0; kt < 4; kt++) {
            int bofs = kt * 4096 + swz * 8;
            #pragma unroll
            for (int j = 0; j < 8; j++) {
                s8v af = *(const s8v*)&Blds[bofs + (j * 16 + mn) * 32];
                acc[j] = MFMA16(af, Bf[kt].v, acc[j]);
            }
        }
        #pragma unroll
        for (int j = 0; j < 8; j++) {
            int h = ct * 128 + j * 16 + q * 4;
            float4 uv = *(const float4*)(urow + h);
            float4 dv = *(const float4*)(D + h);
            float4 o;
            o.x = acc[j][0] + dv.x * uv.x;
            o.y = acc[j][1] + dv.y * uv.y;
            o.z = acc[j][2] + dv.z * uv.z;
            o.w = acc[j][3] + dv.w * uv.w;
            *(float4*)(yrow + h) = o;
        }
    }
}

// -------------------------------------------------------------- launch ----
extern "C" void kernel_launch(void* const* d_in, const int* in_sizes, int n_in,
                              void* d_out, int out_size, void* d_ws, size_t ws_size,
                              hipStream_t stream) {
    const float* u      = (const float*)d_in[0];
    const float* h_r    = (const float*)d_in[1];
    const float* h_i    = (const float*)d_in[2];
    const float* A_real = (const float*)d_in[3];
    const float* A_imag = (const float*)d_in[4];
    const float* B_real = (const float*)d_in[5];
    const float* B_imag = (const float*)d_in[6];
    const float* C_real = (const float*)d_in[7];
    const float* C_imag = (const float*)d_in[8];
    const float* D      = (const float*)d_in[9];
    const float* inv_dt = (const float*)d_in[10];
    float* out = (float*)d_out;

    // workspace layout (floats from base; all 16B aligned)
    float* wsf       = (float*)d_ws;
    float* P_params  = wsf;                    // 256 used, reserve 1024
    float* P_dApow   = wsf + 1024;             // 129*128 = 16512, reserve 16640
    float* P_carry   = wsf + 1024 + 16640;     // 8*NC*128 = 65536
    float* P_end     = P_carry + 65536;        // 65536
    ushort_t* P_W1T  = (ushort_t*)(P_end + 65536);      // 128*1024 bf16 (linear)
    ushort_t* P_Ceff = P_W1T + 128 * 1024;              // 1024*128 bf16 (swizzled)
    float* P_Bu      = (float*)(P_Ceff + 1024 * 128);   // 65536*128 f32 (33.5MB)

    params_kernel<<<1, 64, 0, stream>>>(A_real, A_imag, inv_dt, P_params, P_dApow);
    build_w<<<576, 256, 0, stream>>>(B_real, B_imag, C_real, C_imag, P_params, P_W1T, P_Ceff);
    gemm1s<<<M_TOT / 128, 256, 0, stream>>>(u, P_W1T, P_params, P_dApow, P_Bu, P_end);
    scan_carry<<<8, 64, 0, stream>>>(P_end, P_dApow, h_r, h_i, P_carry);
    gemm2t<<<M_TOT / 64, 256, 0, stream>>>(P_Bu, P_Ceff, u, D, P_dApow, P_carry,
                                           out, out + (size_t)M_TOT * H);
}

// Round 7
// 596.044 us; speedup vs baseline: 1.2628x; 1.0092x over previous
//
#include <hip/hip_runtime.h>

typedef unsigned short ushort_t;
typedef short s8v __attribute__((ext_vector_type(8)));
typedef unsigned short ushort8 __attribute__((ext_vector_type(8)));
typedef float floatx4 __attribute__((ext_vector_type(4)));

#define MFMA16(a, b, c) __builtin_amdgcn_mfma_f32_16x16x32_bf16((a), (b), (c), 0, 0, 0)

static constexpr int B_SZ = 8;
static constexpr int L = 8192;
static constexpr int H = 1024;
static constexpr int M_TOT = B_SZ * L;        // 65536 rows
static constexpr int S_CH = 128;              // chunk length == gemm1 row-tile
static constexpr int NC = L / S_CH;           // 64 chunks per batch

// round-to-nearest-even fp32 -> bf16 bits
__device__ inline ushort_t f2bf(float f) {
    union { float f; unsigned u; } v; v.f = f;
    unsigned r = v.u + 0x7fffu + ((v.u >> 16) & 1u);
    return (ushort_t)(r >> 16);
}

// packed f32x2 -> bf16x2 (RNE) in one instruction
__device__ inline unsigned cvtpk(float lo, float hi) {
    unsigned r;
    asm("v_cvt_pk_bf16_f32 %0, %1, %2" : "=v"(r) : "v"(lo), "v"(hi));
    return r;
}

typedef union { s8v v; unsigned u[4]; } u32x4;

// async global->LDS, 16B per lane; lds dest = wave-uniform base + lane*16
__device__ inline void gload_lds16(const void* g, void* l) {
    __builtin_amdgcn_global_load_lds(
        (const __attribute__((address_space(1))) void*)g,
        (__attribute__((address_space(3))) void*)l, 16, 0, 0);
}

// ---------------------------------------------------------------- params ----
// params[0..63]=dA_r [64..127]=dA_i [128..191]=s_r [192..255]=s_i
// dApow INTERLEAVED: dApow[k*128 + 2p] = Re(dA^k), [k*128+2p+1] = Im(dA^k)
__global__ void params_kernel(const float* __restrict__ A_real,
                              const float* __restrict__ A_imag,
                              const float* __restrict__ inv_dt,
                              float* __restrict__ params,
                              float* __restrict__ dApow) {
    int p = threadIdx.x;  // 64 threads
    float x = inv_dt[p];
    float dt = (x > 20.f) ? x : log1pf(expf(x));
    float ar = A_real[p], ai = A_imag[p];
    float dr = 1.f - 0.5f * dt * ar;
    float di = -0.5f * dt * ai;
    float inv = 1.f / fmaf(dr, dr, di * di);
    float nr = 1.f + 0.5f * dt * ar, ni = 0.5f * dt * ai;
    float dAr = (nr * dr + ni * di) * inv;
    float dAi = (ni * dr - nr * di) * inv;
    params[p]       = dAr;
    params[64 + p]  = dAi;
    params[128 + p] = dt * dr * inv;    // Re(dt/den)
    params[192 + p] = -dt * di * inv;   // Im(dt/den)
    float pr = 1.f, pi = 0.f;
    dApow[2 * p] = 1.f; dApow[2 * p + 1] = 0.f;
    for (int k = 1; k <= S_CH; k++) {
        float npr = pr * dAr - pi * dAi;
        float npi = pr * dAi + pi * dAr;
        pr = npr; pi = npi;
        dApow[k * 128 + 2 * p]     = pr;
        dApow[k * 128 + 2 * p + 1] = pi;
    }
}

// -------------------------------------------------- build bf16 weights ----
// W1T LINEAR rows: W1T[2p][k] = Re(s_p*B[p][k]), W1T[2p+1][k] = Im(...)
// CeffT SWIZZLED granules (16B): byte(granule) = tile*8192 + g*16,
//   g = n*4 + (q ^ ((n>>1)&3)), tile = ct*4 + k/32, n = h%128, ct = h/128.
//   Ceff[h][2p] = 2*Cr[h][p], Ceff[h][2p+1] = -2*Ci[h][p].
__global__ void build_w(const float* __restrict__ Br, const float* __restrict__ Bi,
                        const float* __restrict__ Cr, const float* __restrict__ Ci,
                        const float* __restrict__ params,
                        ushort_t* __restrict__ W1T, ushort_t* __restrict__ CeffT) {
    int t = blockIdx.x * 256 + threadIdx.x;   // 147456 threads
    if (t < 128 * 1024) {
        int n = t >> 10, k = t & 1023;
        int p = n >> 1;
        float sr = params[128 + p], si = params[192 + p];
        float br = Br[p * 1024 + k], bi = Bi[p * 1024 + k];
        float v = (n & 1) ? (sr * bi + si * br) : (sr * br - si * bi);
        W1T[t] = f2bf(v);
    } else {
        int t2 = t - 128 * 1024;              // 16384 granule-threads
        int ct_ti = t2 >> 9, g = t2 & 511;
        int ct = ct_ti >> 2, ti = ct_ti & 3;
        int n = g >> 2;
        int h = ct * 128 + n;
        int qq = (g & 3) ^ ((n >> 1) & 3);
        int kb = ti * 32 + qq * 8;
        ushort8 o;
        #pragma unroll
        for (int e = 0; e < 8; e++) {
            int k = kb + e;
            int p = k >> 1;
            float v = (k & 1) ? -2.f * Ci[h * 64 + p] : 2.f * Cr[h * 64 + p];
            o[e] = f2bf(v);
        }
        *(ushort8*)&CeffT[t2 * 8] = o;
    }
}

// -------------------------------------------- GEMM 1 + fused local scan ----
// (unchanged from round 6)
__global__ __launch_bounds__(256) void gemm1s(const float* __restrict__ u,
                                              const ushort_t* __restrict__ W1T,
                                              const float* __restrict__ params,
                                              const float* __restrict__ dApow,
                                              float* __restrict__ hloc,
                                              float* __restrict__ endbuf) {
    __shared__ float bus[128 * 128];            // 64 KB; aliases staging below
    ushort_t* As = (ushort_t*)bus;              // [128][40] bf16
    ushort_t* Bs = As + 128 * 40;               // [128][40] bf16
    int tid = threadIdx.x;
    int wave = tid >> 6, lane = tid & 63;
    int q = lane >> 4, mn = lane & 15;
    size_t row0 = (size_t)blockIdx.x * 128;
    int r = tid >> 1, half = tid & 1;

    floatx4 acc[2][8] = {};

    for (int kk = 0; kk < 1024; kk += 32) {
        __syncthreads();
        {
            const float4* up = (const float4*)(u + (row0 + r) * 1024 + kk + half * 16);
            float4 f0 = up[0], f1 = up[1], f2 = up[2], f3 = up[3];
            u32x4 t0, t1;
            t0.u[0] = cvtpk(f0.x, f0.y); t0.u[1] = cvtpk(f0.z, f0.w);
            t0.u[2] = cvtpk(f1.x, f1.y); t0.u[3] = cvtpk(f1.z, f1.w);
            t1.u[0] = cvtpk(f2.x, f2.y); t1.u[1] = cvtpk(f2.z, f2.w);
            t1.u[2] = cvtpk(f3.x, f3.y); t1.u[3] = cvtpk(f3.z, f3.w);
            s8v* dst = (s8v*)&As[r * 40 + half * 16];
            dst[0] = t0.v; dst[1] = t1.v;
            const ushort8* wp = (const ushort8*)(W1T + r * 1024 + kk + half * 16);
            ushort8* db = (ushort8*)&Bs[r * 40 + half * 16];
            db[0] = wp[0]; db[1] = wp[1];
        }
        __syncthreads();
        s8v a0 = *(const s8v*)&As[(wave * 32 + mn) * 40 + q * 8];
        s8v a1 = *(const s8v*)&As[(wave * 32 + 16 + mn) * 40 + q * 8];
        #pragma unroll
        for (int j = 0; j < 8; j++) {
            s8v bf = *(const s8v*)&Bs[(j * 16 + mn) * 40 + q * 8];
            acc[0][j] = MFMA16(a0, bf, acc[0][j]);
            acc[1][j] = MFMA16(a1, bf, acc[1][j]);
        }
    }
    __syncthreads();   // staging LDS dead; safe to overwrite with Bu tile
    #pragma unroll
    for (int i = 0; i < 2; i++)
        #pragma unroll
        for (int j = 0; j < 8; j++)
            #pragma unroll
            for (int reg = 0; reg < 4; reg++) {
                int row = wave * 32 + i * 16 + q * 4 + reg;
                bus[row * 128 + j * 16 + mn] = acc[i][j][reg];
            }
    __syncthreads();

    // --- wave-local scan over this wave's 32 rows (zero initial state) ---
    float dAr = params[lane], dAi = params[64 + lane];
    float hr = 0.f, hi = 0.f;
    int base = wave * 32 * 128 + 2 * lane;
    #pragma unroll 8
    for (int t = 0; t < 32; t++) {
        float2 v = *(float2*)&bus[base + t * 128];
        float nhr = fmaf(dAr, hr, fmaf(-dAi, hi, v.x));
        float nhi = fmaf(dAr, hi, fmaf(dAi, hr, v.y));
        hr = nhr; hi = nhi;
        *(float2*)&bus[base + t * 128] = make_float2(hr, hi);
    }
    __syncthreads();

    // --- cross-wave carry: c_w = sum_{w'<w} dA^(32*(w-1-w')) * e_{w'} ---
    float a32r = dApow[32 * 128 + 2 * lane], a32i = dApow[32 * 128 + 2 * lane + 1];
    float cr = 0.f, ci = 0.f;
    for (int w2 = 0; w2 < wave; w2++) {
        float2 e = *(float2*)&bus[(w2 * 32 + 31) * 128 + 2 * lane];
        float tr = fmaf(a32r, cr, fmaf(-a32i, ci, e.x));
        float ti = fmaf(a32r, ci, fmaf(a32i, cr, e.y));
        cr = tr; ci = ti;
    }

    // --- correction + coalesced write: h[l] = h_w[t] + dA^(t+1)*c_w ---
    float* gbase = hloc + (row0 + wave * 32) * 128 + 2 * lane;
    float lr = 0.f, li = 0.f;
    float pr = dAr, pi = dAi;   // dA^1
    #pragma unroll 8
    for (int t = 0; t < 32; t++) {
        float2 v = *(float2*)&bus[base + t * 128];
        float orr = v.x + pr * cr - pi * ci;
        float oi  = v.y + pr * ci + pi * cr;
        *(float2*)(gbase + (size_t)t * 128) = make_float2(orr, oi);
        lr = orr; li = oi;
        float npr = pr * dAr - pi * dAi;
        float npi = pr * dAi + pi * dAr;
        pr = npr; pi = npi;
    }
    if (wave == 3) {   // chunk end state (corrected h at local row 127)
        float* e = endbuf + (size_t)blockIdx.x * 128 + 2 * lane;
        e[0] = lr; e[1] = li;
    }
}

// --------------------------------------------------------- carry scan ----
// (unchanged from round 6)
__global__ void scan_carry(const float* __restrict__ endbuf,
                           const float* __restrict__ dApow,
                           const float* __restrict__ h0r,
                           const float* __restrict__ h0i,
                           float* __restrict__ carry) {
    int t = blockIdx.x * 64 + threadIdx.x;  // 512 = 8*64
    int b = t >> 6, p = t & 63;
    float aSr = dApow[S_CH * 128 + 2 * p], aSi = dApow[S_CH * 128 + 2 * p + 1];
    float cr = h0r[b * 64 + p], ci = h0i[b * 64 + p];
    #pragma unroll
    for (int half = 0; half < 2; half++) {
        float2 e[32];
        #pragma unroll
        for (int c = 0; c < 32; c++)
            e[c] = *(const float2*)(endbuf + ((size_t)b * NC + half * 32 + c) * 128 + 2 * p);
        #pragma unroll
        for (int c = 0; c < 32; c++) {
            int cc = half * 32 + c;
            *(float2*)(carry + ((size_t)b * NC + cc) * 128 + 2 * p) = make_float2(cr, ci);
            float nr = fmaf(aSr, cr, fmaf(-aSi, ci, e[c].x));
            float ni = fmaf(aSr, ci, fmaf(aSi, cr, e[c].y));
            cr = nr; ci = ni;
        }
    }
}

// --------------------------------------------- GEMM 2, transposed output ----
// Same MFMA core as round 6; NEW dense-segment epilogue: per ct, dump acc
// (f32) into padded LDS tile ldsF[64][132] (uniform bank spread), then
// re-read wave-contiguous (lanes 0-31 = one row's 512B) so u-loads and
// y-stores are 512B-dense segments instead of 64x16B scatter. u for the
// first half is issued at the top of each ct (issue-early) to hide HBM
// latency under stage+MFMA. LDS 33.8KB aliased -> still 4 blocks/CU.
__global__ __launch_bounds__(256, 4) void gemm2t(const float* __restrict__ hloc,
                                                 const ushort_t* __restrict__ CeffT,
                                                 const float* __restrict__ u,
                                                 const float* __restrict__ D,
                                                 const float* __restrict__ dApow,
                                                 const float* __restrict__ carry,
                                                 float* __restrict__ y,
                                                 float* __restrict__ out_hlast) {
    __shared__ __align__(16) char smem[64 * 132 * 4];   // 33792 B
    ushort_t* Blds = (ushort_t*)smem;   // Ceff tile (32 KB), phase A
    float* ldsF = (float*)smem;         // transpose tile [64][132], phase B/C
    int tid = threadIdx.x;
    int w = tid >> 6, lane = tid & 63;
    int q = lane >> 4, mn = lane & 15;
    int swz = q ^ ((mn >> 1) & 3);
    size_t row0 = (size_t)blockIdx.x * 64;
    int b = (int)(row0 >> 13);            // batch
    int l0 = (int)(row0 & (L - 1));
    int c = l0 >> 7;                      // chunk (S_CH = 128; 64 | 128)

    int seq = w * 16 + mn;                // local row owned by this lane (MFMA)
    int l = l0 + seq;
    int kp = (l & (S_CH - 1)) + 1;
    const float* hrow = hloc + (row0 + seq) * 128;
    const float* prow = dApow + (size_t)kp * 128;
    const float* crow = carry + ((size_t)b * NC + c) * 128;
    bool last = (l == L - 1);

    // ---- hfix B-fragments (one seq row per lane, k-quarter q), in regs ----
    u32x4 Bf[4];
    #pragma unroll
    for (int kt = 0; kt < 4; kt++) {
        int kb = kt * 32 + q * 8;
        float4 h0 = *(const float4*)(hrow + kb);
        float4 h1 = *(const float4*)(hrow + kb + 4);
        float4 p0 = *(const float4*)(prow + kb);
        float4 p1 = *(const float4*)(prow + kb + 4);
        float4 c0 = *(const float4*)(crow + kb);
        float4 c1 = *(const float4*)(crow + kb + 4);
        float f0 = h0.x + p0.x * c0.x - p0.y * c0.y;
        float f1 = h0.y + p0.x * c0.y + p0.y * c0.x;
        float f2 = h0.z + p0.z * c0.z - p0.w * c0.w;
        float f3 = h0.w + p0.z * c0.w + p0.w * c0.z;
        float f4 = h1.x + p1.x * c1.x - p1.y * c1.y;
        float f5 = h1.y + p1.x * c1.y + p1.y * c1.x;
        float f6 = h1.z + p1.z * c1.z - p1.w * c1.w;
        float f7 = h1.w + p1.z * c1.w + p1.w * c1.z;
        Bf[kt].u[0] = cvtpk(f0, f1); Bf[kt].u[1] = cvtpk(f2, f3);
        Bf[kt].u[2] = cvtpk(f4, f5); Bf[kt].u[3] = cvtpk(f6, f7);
        if (last) {
            int pb = kb >> 1;
            out_hlast[b * 64 + pb]     = f0; out_hlast[512 + b * 64 + pb]     = f1;
            out_hlast[b * 64 + pb + 1] = f2; out_hlast[512 + b * 64 + pb + 1] = f3;
            out_hlast[b * 64 + pb + 2] = f4; out_hlast[512 + b * 64 + pb + 2] = f5;
            out_hlast[b * 64 + pb + 3] = f6; out_hlast[512 + b * 64 + pb + 3] = f7;
        }
    }

    // dense-epilogue lane mapping: rows w*16 + i*2 + (lane>>5), cols (lane&31)*4
    int erow_b = w * 16 + (lane >> 5);    // + i*2 per sub-iteration
    int es4 = lane & 31;                  // float4 column index within 128

    for (int ct = 0; ct < 8; ct++) {
        // issue-early: u for sub-iterations 0..3 (independent of all LDS)
        const float* ub = u + ct * 128 + es4 * 4;
        float4 uv0 = *(const float4*)(ub + (row0 + erow_b + 0) * 1024);
        float4 uv1 = *(const float4*)(ub + (row0 + erow_b + 2) * 1024);
        float4 uv2 = *(const float4*)(ub + (row0 + erow_b + 4) * 1024);
        float4 uv3 = *(const float4*)(ub + (row0 + erow_b + 6) * 1024);
        float4 dvv = *(const float4*)(D + ct * 128 + es4 * 4);

        if (ct) __syncthreads();          // phase-C ldsF reads of ct-1 done
        {   // stage 32KB swizzled CeffT column-tile ct
            const ushort_t* gsrc = CeffT + (size_t)ct * 16384 + w * 512 + lane * 8;
            ushort_t* ldst = Blds + w * 512;
            #pragma unroll
            for (int it = 0; it < 8; it++)
                gload_lds16(gsrc + it * 2048, ldst + it * 2048);
        }
        __syncthreads();                  // Ceff tile ready
        floatx4 acc[8] = {};
        #pragma unroll
        for (int kt = 0; kt < 4; kt++) {
            int bofs = kt * 4096 + swz * 8;
            #pragma unroll
            for (int j = 0; j < 8; j++) {
                s8v af = *(const s8v*)&Blds[bofs + (j * 16 + mn) * 32];
                acc[j] = MFMA16(af, Bf[kt].v, acc[j]);
            }
        }
        __syncthreads();                  // MFMA ds_reads done; Blds dead
        #pragma unroll
        for (int j = 0; j < 8; j++)       // dump: lane owns seq row, h j*16+q*4
            *(floatx4*)&ldsF[(size_t)seq * 132 + j * 16 + q * 4] = acc[j];
        __syncthreads();                  // ldsF ready
        #pragma unroll
        for (int i = 0; i < 8; i++) {     // dense read + u + store
            int row = erow_b + i * 2;
            float4 fv = *(const float4*)&ldsF[(size_t)row * 132 + es4 * 4];
            float4 uvv = (i == 0) ? uv0 : (i == 1) ? uv1 : (i == 2) ? uv2 :
                         (i == 3) ? uv3 :
                         *(const float4*)(ub + (row0 + row) * 1024);
            float4 o;
            o.x = fv.x + dvv.x * uvv.x;
            o.y = fv.y + dvv.y * uvv.y;
            o.z = fv.z + dvv.z * uvv.z;
            o.w = fv.w + dvv.w * uvv.w;
            *(float4*)(y + (row0 + row) * 1024 + ct * 128 + es4 * 4) = o;
        }
    }
}

// -------------------------------------------------------------- launch ----
extern "C" void kernel_launch(void* const* d_in, const int* in_sizes, int n_in,
                              void* d_out, int out_size, void* d_ws, size_t ws_size,
                              hipStream_t stream) {
    const float* u      = (const float*)d_in[0];
    const float* h_r    = (const float*)d_in[1];
    const float* h_i    = (const float*)d_in[2];
    const float* A_real = (const float*)d_in[3];
    const float* A_imag = (const float*)d_in[4];
    const float* B_real = (const float*)d_in[5];
    const float* B_imag = (const float*)d_in[6];
    const float* C_real = (const float*)d_in[7];
    const float* C_imag = (const float*)d_in[8];
    const float* D      = (const float*)d_in[9];
    const float* inv_dt = (const float*)d_in[10];
    float* out = (float*)d_out;

    // workspace layout (floats from base; all 16B aligned)
    float* wsf       = (float*)d_ws;
    float* P_params  = wsf;                    // 256 used, reserve 1024
    float* P_dApow   = wsf + 1024;             // 129*128 = 16512, reserve 16640
    float* P_carry   = wsf + 1024 + 16640;     // 8*NC*128 = 65536
    float* P_end     = P_carry + 65536;        // 65536
    ushort_t* P_W1T  = (ushort_t*)(P_end + 65536);      // 128*1024 bf16 (linear)
    ushort_t* P_Ceff = P_W1T + 128 * 1024;              // 1024*128 bf16 (swizzled)
    float* P_Bu      = (float*)(P_Ceff + 1024 * 128);   // 65536*128 f32 (33.5MB)

    params_kernel<<<1, 64, 0, stream>>>(A_real, A_imag, inv_dt, P_params, P_dApow);
    build_w<<<576, 256, 0, stream>>>(B_real, B_imag, C_real, C_imag, P_params, P_W1T, P_Ceff);
    gemm1s<<<M_TOT / 128, 256, 0, stream>>>(u, P_W1T, P_params, P_dApow, P_Bu, P_end);
    scan_carry<<<8, 64, 0, stream>>>(P_end, P_dApow, h_r, h_i, P_carry);
    gemm2t<<<M_TOT / 64, 256, 0, stream>>>(P_Bu, P_Ceff, u, D, P_dApow, P_carry,
                                           out, out + (size_t)M_TOT * H);
}

// Round 8
// 595.092 us; speedup vs baseline: 1.2648x; 1.0016x over previous
//
#include <hip/hip_runtime.h>

typedef unsigned short ushort_t;
typedef short s8v __attribute__((ext_vector_type(8)));
typedef unsigned short ushort8 __attribute__((ext_vector_type(8)));
typedef float floatx4 __attribute__((ext_vector_type(4)));

#define MFMA16(a, b, c) __builtin_amdgcn_mfma_f32_16x16x32_bf16((a), (b), (c), 0, 0, 0)

static constexpr int B_SZ = 8;
static constexpr int L = 8192;
static constexpr int H = 1024;
static constexpr int M_TOT = B_SZ * L;        // 65536 rows
static constexpr int S_CH = 128;              // chunk length == gemm1 row-tile
static constexpr int NC = L / S_CH;           // 64 chunks per batch

// round-to-nearest-even fp32 -> bf16 bits
__device__ inline ushort_t f2bf(float f) {
    union { float f; unsigned u; } v; v.f = f;
    unsigned r = v.u + 0x7fffu + ((v.u >> 16) & 1u);
    return (ushort_t)(r >> 16);
}

// packed f32x2 -> bf16x2 (RNE) in one instruction
__device__ inline unsigned cvtpk(float lo, float hi) {
    unsigned r;
    asm("v_cvt_pk_bf16_f32 %0, %1, %2" : "=v"(r) : "v"(lo), "v"(hi));
    return r;
}

typedef union { s8v v; unsigned u[4]; } u32x4;

// async global->LDS, 16B per lane; lds dest = wave-uniform base + lane*16
__device__ inline void gload_lds16(const void* g, void* l) {
    __builtin_amdgcn_global_load_lds(
        (const __attribute__((address_space(1))) void*)g,
        (__attribute__((address_space(3))) void*)l, 16, 0, 0);
}

// ---------------------------------------------------------------- params ----
// params[0..63]=dA_r [64..127]=dA_i [128..191]=s_r [192..255]=s_i
// dApow INTERLEAVED: dApow[k*128 + 2p] = Re(dA^k), [k*128+2p+1] = Im(dA^k)
__global__ void params_kernel(const float* __restrict__ A_real,
                              const float* __restrict__ A_imag,
                              const float* __restrict__ inv_dt,
                              float* __restrict__ params,
                              float* __restrict__ dApow) {
    int p = threadIdx.x;  // 64 threads
    float x = inv_dt[p];
    float dt = (x > 20.f) ? x : log1pf(expf(x));
    float ar = A_real[p], ai = A_imag[p];
    float dr = 1.f - 0.5f * dt * ar;
    float di = -0.5f * dt * ai;
    float inv = 1.f / fmaf(dr, dr, di * di);
    float nr = 1.f + 0.5f * dt * ar, ni = 0.5f * dt * ai;
    float dAr = (nr * dr + ni * di) * inv;
    float dAi = (ni * dr - nr * di) * inv;
    params[p]       = dAr;
    params[64 + p]  = dAi;
    params[128 + p] = dt * dr * inv;    // Re(dt/den)
    params[192 + p] = -dt * di * inv;   // Im(dt/den)
    float pr = 1.f, pi = 0.f;
    dApow[2 * p] = 1.f; dApow[2 * p + 1] = 0.f;
    for (int k = 1; k <= S_CH; k++) {
        float npr = pr * dAr - pi * dAi;
        float npi = pr * dAi + pi * dAr;
        pr = npr; pi = npi;
        dApow[k * 128 + 2 * p]     = pr;
        dApow[k * 128 + 2 * p + 1] = pi;
    }
}

// -------------------------------------------------- build bf16 weights ----
// W1T LINEAR rows: W1T[2p][k] = Re(s_p*B[p][k]), W1T[2p+1][k] = Im(...)
// CeffT SWIZZLED granules (16B): byte(granule) = tile*8192 + g*16,
//   g = n*4 + (q ^ ((n>>1)&3)), tile = ct*4 + k/32, n = h%128, ct = h/128.
//   Ceff[h][2p] = 2*Cr[h][p], Ceff[h][2p+1] = -2*Ci[h][p].
__global__ void build_w(const float* __restrict__ Br, const float* __restrict__ Bi,
                        const float* __restrict__ Cr, const float* __restrict__ Ci,
                        const float* __restrict__ params,
                        ushort_t* __restrict__ W1T, ushort_t* __restrict__ CeffT) {
    int t = blockIdx.x * 256 + threadIdx.x;   // 147456 threads
    if (t < 128 * 1024) {
        int n = t >> 10, k = t & 1023;
        int p = n >> 1;
        float sr = params[128 + p], si = params[192 + p];
        float br = Br[p * 1024 + k], bi = Bi[p * 1024 + k];
        float v = (n & 1) ? (sr * bi + si * br) : (sr * br - si * bi);
        W1T[t] = f2bf(v);
    } else {
        int t2 = t - 128 * 1024;              // 16384 granule-threads
        int ct_ti = t2 >> 9, g = t2 & 511;
        int ct = ct_ti >> 2, ti = ct_ti & 3;
        int n = g >> 2;
        int h = ct * 128 + n;
        int qq = (g & 3) ^ ((n >> 1) & 3);
        int kb = ti * 32 + qq * 8;
        ushort8 o;
        #pragma unroll
        for (int e = 0; e < 8; e++) {
            int k = kb + e;
            int p = k >> 1;
            float v = (k & 1) ? -2.f * Ci[h * 64 + p] : 2.f * Cr[h * 64 + p];
            o[e] = f2bf(v);
        }
        *(ushort8*)&CeffT[t2 * 8] = o;
    }
}

// -------------------------------------------- GEMM 1 + fused local scan ----
// NEW K-loop: double-buffered global_load_lds pipeline, ONE barrier/K-step.
//  A (u) f32 in LDS, XOR-swizzled via pre-swizzled per-lane global source
//  (byte ^= (row&7)<<4 within row); frag = 2x ds_read_b128 + 4 cvtpk per row.
//  B (W1T) bf16 in LDS, linear. STAGE(next) issued before ds_read+MFMA(cur);
//  __syncthreads() drains vmcnt -> prefetch latency hides under compute.
// Scan epilogue unchanged (bus aliases the staging LDS).
__global__ __launch_bounds__(256) void gemm1s(const float* __restrict__ u,
                                              const ushort_t* __restrict__ W1T,
                                              const float* __restrict__ params,
                                              const float* __restrict__ dApow,
                                              float* __restrict__ hloc,
                                              float* __restrict__ endbuf) {
    __shared__ __align__(16) char smem[65536];
    // [0,32768): A dbuf 2 x 16KB  ([row][32] f32, XOR-swizzled granules)
    // [32768,49152): B dbuf 2 x 8KB ([n][32] bf16, linear)
    // scan phase: bus = (float*)smem, 64KB
    float* bus = (float*)smem;
    int tid = threadIdx.x;
    int wave = tid >> 6, lane = tid & 63;
    int q = lane >> 4, mn = lane & 15;
    size_t row0 = (size_t)blockIdx.x * 128;

    // staging lane constants
    int srA = lane >> 3;                       // row within 8-row chunk
    int sinA = (((lane & 7) ^ srA) << 4);      // pre-swizzled in-row byte
    int srB = lane >> 2;                       // n within 16-row chunk
    int sinB = (lane & 3) << 4;                // in-row byte (16B units)

    floatx4 acc[2][8] = {};

    // A-frag read constants
    int r0 = wave * 32 + mn;
    int maskA = (r0 & 7) << 4;                 // same for r0 and r0+16
    int ya0 = r0 * 128 + q * 32;
    int ya1 = (r0 + 16) * 128 + q * 32;

    #define STAGE1(buf, kk)                                                     \
        do {                                                                    \
            _Pragma("unroll")                                                   \
            for (int i_ = 0; i_ < 4; i_++) {                                    \
                int c_ = i_ * 4 + wave;                                         \
                const char* g_ = (const char*)u +                               \
                    (row0 + c_ * 8 + srA) * 4096 + (kk) * 4 + sinA;             \
                gload_lds16(g_, smem + (buf) * 16384 + c_ * 1024);              \
            }                                                                   \
            _Pragma("unroll")                                                   \
            for (int i_ = 0; i_ < 2; i_++) {                                    \
                int c_ = i_ * 4 + wave;                                         \
                const char* g_ = (const char*)W1T +                             \
                    (size_t)(c_ * 16 + srB) * 2048 + (kk) * 2 + sinB;           \
                gload_lds16(g_, smem + 32768 + (buf) * 8192 + c_ * 1024);       \
            }                                                                   \
        } while (0)

    STAGE1(0, 0);
    __syncthreads();                            // buf0 ready
    int cur = 0;
    for (int t = 0; t < 32; t++) {
        if (t < 31) STAGE1(cur ^ 1, (t + 1) * 32);   // async prefetch next
        const char* abase = smem + cur * 16384;
        floatx4 v00 = *(const floatx4*)(abase + (ya0 ^ maskA));
        floatx4 v01 = *(const floatx4*)(abase + ((ya0 + 16) ^ maskA));
        floatx4 v10 = *(const floatx4*)(abase + (ya1 ^ maskA));
        floatx4 v11 = *(const floatx4*)(abase + ((ya1 + 16) ^ maskA));
        u32x4 a0, a1;
        a0.u[0] = cvtpk(v00[0], v00[1]); a0.u[1] = cvtpk(v00[2], v00[3]);
        a0.u[2] = cvtpk(v01[0], v01[1]); a0.u[3] = cvtpk(v01[2], v01[3]);
        a1.u[0] = cvtpk(v10[0], v10[1]); a1.u[1] = cvtpk(v10[2], v10[3]);
        a1.u[2] = cvtpk(v11[0], v11[1]); a1.u[3] = cvtpk(v11[2], v11[3]);
        const ushort_t* bb = (const ushort_t*)(smem + 32768 + cur * 8192);
        #pragma unroll
        for (int j = 0; j < 8; j++) {
            s8v bf = *(const s8v*)(bb + (j * 16 + mn) * 32 + q * 8);
            acc[0][j] = MFMA16(a0.v, bf, acc[0][j]);
            acc[1][j] = MFMA16(a1.v, bf, acc[1][j]);
        }
        __syncthreads();                        // drains vmcnt: next buf ready
        cur ^= 1;
    }
    #undef STAGE1

    // --- dump acc to LDS bus (staging LDS dead) ---
    #pragma unroll
    for (int i = 0; i < 2; i++)
        #pragma unroll
        for (int j = 0; j < 8; j++)
            #pragma unroll
            for (int reg = 0; reg < 4; reg++) {
                int row = wave * 32 + i * 16 + q * 4 + reg;
                bus[row * 128 + j * 16 + mn] = acc[i][j][reg];
            }
    __syncthreads();

    // --- wave-local scan over this wave's 32 rows (zero initial state) ---
    float dAr = params[lane], dAi = params[64 + lane];
    float hr = 0.f, hi = 0.f;
    int base = wave * 32 * 128 + 2 * lane;
    #pragma unroll 8
    for (int t = 0; t < 32; t++) {
        float2 v = *(float2*)&bus[base + t * 128];
        float nhr = fmaf(dAr, hr, fmaf(-dAi, hi, v.x));
        float nhi = fmaf(dAr, hi, fmaf(dAi, hr, v.y));
        hr = nhr; hi = nhi;
        *(float2*)&bus[base + t * 128] = make_float2(hr, hi);
    }
    __syncthreads();

    // --- cross-wave carry: c_w = sum_{w'<w} dA^(32*(w-1-w')) * e_{w'} ---
    float a32r = dApow[32 * 128 + 2 * lane], a32i = dApow[32 * 128 + 2 * lane + 1];
    float cr = 0.f, ci = 0.f;
    for (int w2 = 0; w2 < wave; w2++) {
        float2 e = *(float2*)&bus[(w2 * 32 + 31) * 128 + 2 * lane];
        float tr = fmaf(a32r, cr, fmaf(-a32i, ci, e.x));
        float ti = fmaf(a32r, ci, fmaf(a32i, cr, e.y));
        cr = tr; ci = ti;
    }

    // --- correction + coalesced write: h[l] = h_w[t] + dA^(t+1)*c_w ---
    float* gbase = hloc + (row0 + wave * 32) * 128 + 2 * lane;
    float lr = 0.f, li = 0.f;
    float pr = dAr, pi = dAi;   // dA^1
    #pragma unroll 8
    for (int t = 0; t < 32; t++) {
        float2 v = *(float2*)&bus[base + t * 128];
        float orr = v.x + pr * cr - pi * ci;
        float oi  = v.y + pr * ci + pi * cr;
        *(float2*)(gbase + (size_t)t * 128) = make_float2(orr, oi);
        lr = orr; li = oi;
        float npr = pr * dAr - pi * dAi;
        float npi = pr * dAi + pi * dAr;
        pr = npr; pi = npi;
    }
    if (wave == 3) {   // chunk end state (corrected h at local row 127)
        float* e = endbuf + (size_t)blockIdx.x * 128 + 2 * lane;
        e[0] = lr; e[1] = li;
    }
}

// --------------------------------------------------------- carry scan ----
// (unchanged)
__global__ void scan_carry(const float* __restrict__ endbuf,
                           const float* __restrict__ dApow,
                           const float* __restrict__ h0r,
                           const float* __restrict__ h0i,
                           float* __restrict__ carry) {
    int t = blockIdx.x * 64 + threadIdx.x;  // 512 = 8*64
    int b = t >> 6, p = t & 63;
    float aSr = dApow[S_CH * 128 + 2 * p], aSi = dApow[S_CH * 128 + 2 * p + 1];
    float cr = h0r[b * 64 + p], ci = h0i[b * 64 + p];
    #pragma unroll
    for (int half = 0; half < 2; half++) {
        float2 e[32];
        #pragma unroll
        for (int c = 0; c < 32; c++)
            e[c] = *(const float2*)(endbuf + ((size_t)b * NC + half * 32 + c) * 128 + 2 * p);
        #pragma unroll
        for (int c = 0; c < 32; c++) {
            int cc = half * 32 + c;
            *(float2*)(carry + ((size_t)b * NC + cc) * 128 + 2 * p) = make_float2(cr, ci);
            float nr = fmaf(aSr, cr, fmaf(-aSi, ci, e[c].x));
            float ni = fmaf(aSr, ci, fmaf(aSi, cr, e[c].y));
            cr = nr; ci = ni;
        }
    }
}

// --------------------------------------------- GEMM 2, transposed output ----
// (unchanged from round 7)
__global__ __launch_bounds__(256, 4) void gemm2t(const float* __restrict__ hloc,
                                                 const ushort_t* __restrict__ CeffT,
                                                 const float* __restrict__ u,
                                                 const float* __restrict__ D,
                                                 const float* __restrict__ dApow,
                                                 const float* __restrict__ carry,
                                                 float* __restrict__ y,
                                                 float* __restrict__ out_hlast) {
    __shared__ __align__(16) char smem[64 * 132 * 4];   // 33792 B
    ushort_t* Blds = (ushort_t*)smem;   // Ceff tile (32 KB), phase A
    float* ldsF = (float*)smem;         // transpose tile [64][132], phase B/C
    int tid = threadIdx.x;
    int w = tid >> 6, lane = tid & 63;
    int q = lane >> 4, mn = lane & 15;
    int swz = q ^ ((mn >> 1) & 3);
    size_t row0 = (size_t)blockIdx.x * 64;
    int b = (int)(row0 >> 13);            // batch
    int l0 = (int)(row0 & (L - 1));
    int c = l0 >> 7;                      // chunk (S_CH = 128; 64 | 128)

    int seq = w * 16 + mn;                // local row owned by this lane (MFMA)
    int l = l0 + seq;
    int kp = (l & (S_CH - 1)) + 1;
    const float* hrow = hloc + (row0 + seq) * 128;
    const float* prow = dApow + (size_t)kp * 128;
    const float* crow = carry + ((size_t)b * NC + c) * 128;
    bool last = (l == L - 1);

    // ---- hfix B-fragments (one seq row per lane, k-quarter q), in regs ----
    u32x4 Bf[4];
    #pragma unroll
    for (int kt = 0; kt < 4; kt++) {
        int kb = kt * 32 + q * 8;
        float4 h0 = *(const float4*)(hrow + kb);
        float4 h1 = *(const float4*)(hrow + kb + 4);
        float4 p0 = *(const float4*)(prow + kb);
        float4 p1 = *(const float4*)(prow + kb + 4);
        float4 c0 = *(const float4*)(crow + kb);
        float4 c1 = *(const float4*)(crow + kb + 4);
        float f0 = h0.x + p0.x * c0.x - p0.y * c0.y;
        float f1 = h0.y + p0.x * c0.y + p0.y * c0.x;
        float f2 = h0.z + p0.z * c0.z - p0.w * c0.w;
        float f3 = h0.w + p0.z * c0.w + p0.w * c0.z;
        float f4 = h1.x + p1.x * c1.x - p1.y * c1.y;
        float f5 = h1.y + p1.x * c1.y + p1.y * c1.x;
        float f6 = h1.z + p1.z * c1.z - p1.w * c1.w;
        float f7 = h1.w + p1.z * c1.w + p1.w * c1.z;
        Bf[kt].u[0] = cvtpk(f0, f1); Bf[kt].u[1] = cvtpk(f2, f3);
        Bf[kt].u[2] = cvtpk(f4, f5); Bf[kt].u[3] = cvtpk(f6, f7);
        if (last) {
            int pb = kb >> 1;
            out_hlast[b * 64 + pb]     = f0; out_hlast[512 + b * 64 + pb]     = f1;
            out_hlast[b * 64 + pb + 1] = f2; out_hlast[512 + b * 64 + pb + 1] = f3;
            out_hlast[b * 64 + pb + 2] = f4; out_hlast[512 + b * 64 + pb + 2] = f5;
            out_hlast[b * 64 + pb + 3] = f6; out_hlast[512 + b * 64 + pb + 3] = f7;
        }
    }

    // dense-epilogue lane mapping: rows w*16 + i*2 + (lane>>5), cols (lane&31)*4
    int erow_b = w * 16 + (lane >> 5);    // + i*2 per sub-iteration
    int es4 = lane & 31;                  // float4 column index within 128

    for (int ct = 0; ct < 8; ct++) {
        // issue-early: u for sub-iterations 0..3 (independent of all LDS)
        const float* ub = u + ct * 128 + es4 * 4;
        float4 uv0 = *(const float4*)(ub + (row0 + erow_b + 0) * 1024);
        float4 uv1 = *(const float4*)(ub + (row0 + erow_b + 2) * 1024);
        float4 uv2 = *(const float4*)(ub + (row0 + erow_b + 4) * 1024);
        float4 uv3 = *(const float4*)(ub + (row0 + erow_b + 6) * 1024);
        float4 dvv = *(const float4*)(D + ct * 128 + es4 * 4);

        if (ct) __syncthreads();          // phase-C ldsF reads of ct-1 done
        {   // stage 32KB swizzled CeffT column-tile ct
            const ushort_t* gsrc = CeffT + (size_t)ct * 16384 + w * 512 + lane * 8;
            ushort_t* ldst = Blds + w * 512;
            #pragma unroll
            for (int it = 0; it < 8; it++)
                gload_lds16(gsrc + it * 2048, ldst + it * 2048);
        }
        __syncthreads();                  // Ceff tile ready
        floatx4 acc[8] = {};
        #pragma unroll
        for (int kt = 0; kt < 4; kt++) {
            int bofs = kt * 4096 + swz * 8;
            #pragma unroll
            for (int j = 0; j < 8; j++) {
                s8v af = *(const s8v*)&Blds[bofs + (j * 16 + mn) * 32];
                acc[j] = MFMA16(af, Bf[kt].v, acc[j]);
            }
        }
        __syncthreads();                  // MFMA ds_reads done; Blds dead
        #pragma unroll
        for (int j = 0; j < 8; j++)       // dump: lane owns seq row, h j*16+q*4
            *(floatx4*)&ldsF[(size_t)seq * 132 + j * 16 + q * 4] = acc[j];
        __syncthreads();                  // ldsF ready
        #pragma unroll
        for (int i = 0; i < 8; i++) {     // dense read + u + store
            int row = erow_b + i * 2;
            float4 fv = *(const float4*)&ldsF[(size_t)row * 132 + es4 * 4];
            float4 uvv = (i == 0) ? uv0 : (i == 1) ? uv1 : (i == 2) ? uv2 :
                         (i == 3) ? uv3 :
                         *(const float4*)(ub + (row0 + row) * 1024);
            float4 o;
            o.x = fv.x + dvv.x * uvv.x;
            o.y = fv.y + dvv.y * uvv.y;
            o.z = fv.z + dvv.z * uvv.z;
            o.w = fv.w + dvv.w * uvv.w;
            *(float4*)(y + (row0 + row) * 1024 + ct * 128 + es4 * 4) = o;
        }
    }
}

// -------------------------------------------------------------- launch ----
extern "C" void kernel_launch(void* const* d_in, const int* in_sizes, int n_in,
                              void* d_out, int out_size, void* d_ws, size_t ws_size,
                              hipStream_t stream) {
    const float* u      = (const float*)d_in[0];
    const float* h_r    = (const float*)d_in[1];
    const float* h_i    = (const float*)d_in[2];
    const float* A_real = (const float*)d_in[3];
    const float* A_imag = (const float*)d_in[4];
    const float* B_real = (const float*)d_in[5];
    const float* B_imag = (const float*)d_in[6];
    const float* C_real = (const float*)d_in[7];
    const float* C_imag = (const float*)d_in[8];
    const float* D      = (const float*)d_in[9];
    const float* inv_dt = (const float*)d_in[10];
    float* out = (float*)d_out;

    // workspace layout (floats from base; all 16B aligned)
    float* wsf       = (float*)d_ws;
    float* P_params  = wsf;                    // 256 used, reserve 1024
    float* P_dApow   = wsf + 1024;             // 129*128 = 16512, reserve 16640
    float* P_carry   = wsf + 1024 + 16640;     // 8*NC*128 = 65536
    float* P_end     = P_carry + 65536;        // 65536
    ushort_t* P_W1T  = (ushort_t*)(P_end + 65536);      // 128*1024 bf16 (linear)
    ushort_t* P_Ceff = P_W1T + 128 * 1024;              // 1024*128 bf16 (swizzled)
    float* P_Bu      = (float*)(P_Ceff + 1024 * 128);   // 65536*128 f32 (33.5MB)

    params_kernel<<<1, 64, 0, stream>>>(A_real, A_imag, inv_dt, P_params, P_dApow);
    build_w<<<576, 256, 0, stream>>>(B_real, B_imag, C_real, C_imag, P_params, P_W1T, P_Ceff);
    gemm1s<<<M_TOT / 128, 256, 0, stream>>>(u, P_W1T, P_params, P_dApow, P_Bu, P_end);
    scan_carry<<<8, 64, 0, stream>>>(P_end, P_dApow, h_r, h_i, P_carry);
    gemm2t<<<M_TOT / 64, 256, 0, stream>>>(P_Bu, P_Ceff, u, D, P_dApow, P_carry,
                                           out, out + (size_t)M_TOT * H);
}

// Round 10
// 592.667 us; speedup vs baseline: 1.2700x; 1.0041x over previous
//
#include <hip/hip_runtime.h>

typedef unsigned short ushort_t;
typedef short s8v __attribute__((ext_vector_type(8)));
typedef unsigned short ushort8 __attribute__((ext_vector_type(8)));
typedef float floatx4 __attribute__((ext_vector_type(4)));

#define MFMA16(a, b, c) __builtin_amdgcn_mfma_f32_16x16x32_bf16((a), (b), (c), 0, 0, 0)

static constexpr int B_SZ = 8;
static constexpr int L = 8192;
static constexpr int H = 1024;
static constexpr int M_TOT = B_SZ * L;        // 65536 rows
static constexpr int S_CH = 64;               // chunk length == gemm1 row-tile
static constexpr int NC = L / S_CH;           // 128 chunks per batch

// round-to-nearest-even fp32 -> bf16 bits
__device__ inline ushort_t f2bf(float f) {
    union { float f; unsigned u; } v; v.f = f;
    unsigned r = v.u + 0x7fffu + ((v.u >> 16) & 1u);
    return (ushort_t)(r >> 16);
}

// packed f32x2 -> bf16x2 (RNE) in one instruction
__device__ inline unsigned cvtpk(float lo, float hi) {
    unsigned r;
    asm("v_cvt_pk_bf16_f32 %0, %1, %2" : "=v"(r) : "v"(lo), "v"(hi));
    return r;
}

typedef union { s8v v; unsigned u[4]; } u32x4;

// async global->LDS, 16B per lane; lds dest = wave-uniform base + lane*16
__device__ inline void gload_lds16(const void* g, void* l) {
    __builtin_amdgcn_global_load_lds(
        (const __attribute__((address_space(1))) void*)g,
        (__attribute__((address_space(3))) void*)l, 16, 0, 0);
}

// ---------------------------------------------------------------- params ----
// params[0..63]=dA_r [64..127]=dA_i [128..191]=s_r [192..255]=s_i
// dApow INTERLEAVED: dApow[k*128 + 2p] = Re(dA^k), [k*128+2p+1] = Im(dA^k),
// k = 0..S_CH (=64)
__global__ void params_kernel(const float* __restrict__ A_real,
                              const float* __restrict__ A_imag,
                              const float* __restrict__ inv_dt,
                              float* __restrict__ params,
                              float* __restrict__ dApow) {
    int p = threadIdx.x;  // 64 threads
    float x = inv_dt[p];
    float dt = (x > 20.f) ? x : log1pf(expf(x));
    float ar = A_real[p], ai = A_imag[p];
    float dr = 1.f - 0.5f * dt * ar;
    float di = -0.5f * dt * ai;
    float inv = 1.f / fmaf(dr, dr, di * di);
    float nr = 1.f + 0.5f * dt * ar, ni = 0.5f * dt * ai;
    float dAr = (nr * dr + ni * di) * inv;
    float dAi = (ni * dr - nr * di) * inv;
    params[p]       = dAr;
    params[64 + p]  = dAi;
    params[128 + p] = dt * dr * inv;    // Re(dt/den)
    params[192 + p] = -dt * di * inv;   // Im(dt/den)
    float pr = 1.f, pi = 0.f;
    dApow[2 * p] = 1.f; dApow[2 * p + 1] = 0.f;
    for (int k = 1; k <= S_CH; k++) {
        float npr = pr * dAr - pi * dAi;
        float npi = pr * dAi + pi * dAr;
        pr = npr; pi = npi;
        dApow[k * 128 + 2 * p]     = pr;
        dApow[k * 128 + 2 * p + 1] = pi;
    }
}

// -------------------------------------------------- build bf16 weights ----
// W1T LINEAR rows: W1T[2p][k] = Re(s_p*B[p][k]), W1T[2p+1][k] = Im(...)
// CeffT SWIZZLED granules (16B): byte(granule) = tile*8192 + g*16,
//   g = n*4 + (q ^ ((n>>1)&3)), tile = ct*4 + k/32, n = h%128, ct = h/128.
//   Ceff[h][2p] = 2*Cr[h][p], Ceff[h][2p+1] = -2*Ci[h][p].
__global__ void build_w(const float* __restrict__ Br, const float* __restrict__ Bi,
                        const float* __restrict__ Cr, const float* __restrict__ Ci,
                        const float* __restrict__ params,
                        ushort_t* __restrict__ W1T, ushort_t* __restrict__ CeffT) {
    int t = blockIdx.x * 256 + threadIdx.x;   // 147456 threads
    if (t < 128 * 1024) {
        int n = t >> 10, k = t & 1023;
        int p = n >> 1;
        float sr = params[128 + p], si = params[192 + p];
        float br = Br[p * 1024 + k], bi = Bi[p * 1024 + k];
        float v = (n & 1) ? (sr * bi + si * br) : (sr * br - si * bi);
        W1T[t] = f2bf(v);
    } else {
        int t2 = t - 128 * 1024;              // 16384 granule-threads
        int ct_ti = t2 >> 9, g = t2 & 511;
        int ct = ct_ti >> 2, ti = ct_ti & 3;
        int n = g >> 2;
        int h = ct * 128 + n;
        int qq = (g & 3) ^ ((n >> 1) & 3);
        int kb = ti * 32 + qq * 8;
        ushort8 o;
        #pragma unroll
        for (int e = 0; e < 8; e++) {
            int k = kb + e;
            int p = k >> 1;
            float v = (k & 1) ? -2.f * Ci[h * 64 + p] : 2.f * Cr[h * 64 + p];
            o[e] = f2bf(v);
        }
        *(ushort8*)&CeffT[t2 * 8] = o;
    }
}

// -------------------------------------------- GEMM 1 + fused local scan ----
// 64-row tiles, grid 1024 = 4 blocks/CU (2x TLP vs R8's 2/CU). Same verified
// pipelined staging: A (u) f32 XOR-swizzled to LDS via pre-swizzled global
// source; B (W1T) bf16 linear; double-buffered, 1 barrier/K-step. Each wave
// owns one 16-row MFMA sub-tile. Scan: 16 steps/wave, cross-wave dA^16.
__global__ __launch_bounds__(256, 4) void gemm1s(const float* __restrict__ u,
                                                 const ushort_t* __restrict__ W1T,
                                                 const float* __restrict__ params,
                                                 const float* __restrict__ dApow,
                                                 float* __restrict__ hloc,
                                                 float* __restrict__ endbuf) {
    __shared__ __align__(16) char smem[32768];
    // [0,16K): A dbuf 2 x 8KB ([row][32] f32, XOR-swizzled granules)
    // [16K,32K): B dbuf 2 x 8KB ([n][32] bf16, linear)
    // scan phase: bus = (float*)smem, 32KB (64 rows x 128 cols)
    float* bus = (float*)smem;
    int tid = threadIdx.x;
    int wave = tid >> 6, lane = tid & 63;
    int q = lane >> 4, mn = lane & 15;
    size_t row0 = (size_t)blockIdx.x * 64;

    // staging lane constants
    int srA = lane >> 3;                       // row within 8-row chunk
    int sinA = (((lane & 7) ^ srA) << 4);      // pre-swizzled in-row byte
    int srB = lane >> 2;                       // n within 16-row chunk
    int sinB = (lane & 3) << 4;                // in-row byte

    floatx4 acc[8] = {};

    // A-frag read constants (16 rows per wave)
    int r0 = wave * 16 + mn;
    int maskA = (r0 & 7) << 4;
    int ya0 = r0 * 128 + q * 32;

    #define STAGE1(buf, kk)                                                     \
        do {                                                                    \
            _Pragma("unroll")                                                   \
            for (int i_ = 0; i_ < 2; i_++) {                                    \
                int c_ = i_ * 4 + wave;                                         \
                const char* g_ = (const char*)u +                               \
                    (row0 + c_ * 8 + srA) * 4096 + (kk) * 4 + sinA;             \
                gload_lds16(g_, smem + (buf) * 8192 + c_ * 1024);               \
            }                                                                   \
            _Pragma("unroll")                                                   \
            for (int i_ = 0; i_ < 2; i_++) {                                    \
                int c_ = i_ * 4 + wave;                                         \
                const char* g_ = (const char*)W1T +                             \
                    (size_t)(c_ * 16 + srB) * 2048 + (kk) * 2 + sinB;           \
                gload_lds16(g_, smem + 16384 + (buf) * 8192 + c_ * 1024);       \
            }                                                                   \
        } while (0)

    STAGE1(0, 0);
    __syncthreads();                            // buf0 ready
    int cur = 0;
    for (int t = 0; t < 32; t++) {
        if (t < 31) STAGE1(cur ^ 1, (t + 1) * 32);   // async prefetch next
        const char* abase = smem + cur * 8192;
        floatx4 v00 = *(const floatx4*)(abase + (ya0 ^ maskA));
        floatx4 v01 = *(const floatx4*)(abase + ((ya0 + 16) ^ maskA));
        u32x4 a0;
        a0.u[0] = cvtpk(v00[0], v00[1]); a0.u[1] = cvtpk(v00[2], v00[3]);
        a0.u[2] = cvtpk(v01[0], v01[1]); a0.u[3] = cvtpk(v01[2], v01[3]);
        const ushort_t* bb = (const ushort_t*)(smem + 16384 + cur * 8192);
        #pragma unroll
        for (int j = 0; j < 8; j++) {
            s8v bf = *(const s8v*)(bb + (j * 16 + mn) * 32 + q * 8);
            acc[j] = MFMA16(a0.v, bf, acc[j]);
        }
        __syncthreads();                        // drains vmcnt: next buf ready
        cur ^= 1;
    }
    #undef STAGE1

    // --- dump acc to LDS bus (staging LDS dead) ---
    #pragma unroll
    for (int j = 0; j < 8; j++)
        #pragma unroll
        for (int reg = 0; reg < 4; reg++) {
            int row = wave * 16 + q * 4 + reg;
            bus[row * 128 + j * 16 + mn] = acc[j][reg];
        }
    __syncthreads();

    // --- wave-local scan over this wave's 16 rows (zero initial state) ---
    float dAr = params[lane], dAi = params[64 + lane];
    float hr = 0.f, hi = 0.f;
    int base = wave * 16 * 128 + 2 * lane;
    #pragma unroll 8
    for (int t = 0; t < 16; t++) {
        float2 v = *(float2*)&bus[base + t * 128];
        float nhr = fmaf(dAr, hr, fmaf(-dAi, hi, v.x));
        float nhi = fmaf(dAr, hi, fmaf(dAi, hr, v.y));
        hr = nhr; hi = nhi;
        *(float2*)&bus[base + t * 128] = make_float2(hr, hi);
    }
    __syncthreads();

    // --- cross-wave carry: c_w = sum_{w'<w} dA^(16*(w-1-w')) * e_{w'} ---
    float a16r = dApow[16 * 128 + 2 * lane], a16i = dApow[16 * 128 + 2 * lane + 1];
    float cr = 0.f, ci = 0.f;
    for (int w2 = 0; w2 < wave; w2++) {
        float2 e = *(float2*)&bus[(w2 * 16 + 15) * 128 + 2 * lane];
        float tr = fmaf(a16r, cr, fmaf(-a16i, ci, e.x));
        float ti = fmaf(a16r, ci, fmaf(a16i, cr, e.y));
        cr = tr; ci = ti;
    }

    // --- correction + coalesced global write: h[t] = h_w[t] + dA^(t+1)*c_w ---
    float* gbase = hloc + (row0 + wave * 16) * 128 + 2 * lane;
    float lr = 0.f, li = 0.f;
    float pr = dAr, pi = dAi;   // dA^1
    #pragma unroll 8
    for (int t = 0; t < 16; t++) {
        float2 v = *(float2*)&bus[base + t * 128];
        float orr = v.x + pr * cr - pi * ci;
        float oi  = v.y + pr * ci + pi * cr;
        *(float2*)(gbase + (size_t)t * 128) = make_float2(orr, oi);
        lr = orr; li = oi;
        float npr = pr * dAr - pi * dAi;
        float npi = pr * dAi + pi * dAr;
        pr = npr; pi = npi;
    }
    if (wave == 3) {   // chunk end state (corrected h at local row 63)
        float* e = endbuf + (size_t)blockIdx.x * 128 + 2 * lane;
        e[0] = lr; e[1] = li;
    }
}

// --------------------------------------------------------- carry scan ----
// carry[c] = state entering chunk c; carry[0] = h0. NC=128: 4 batches of 32
// independent loads, serial chain in-register.
__global__ void scan_carry(const float* __restrict__ endbuf,
                           const float* __restrict__ dApow,
                           const float* __restrict__ h0r,
                           const float* __restrict__ h0i,
                           float* __restrict__ carry) {
    int t = blockIdx.x * 64 + threadIdx.x;  // 512 = 8*64
    int b = t >> 6, p = t & 63;
    float aSr = dApow[S_CH * 128 + 2 * p], aSi = dApow[S_CH * 128 + 2 * p + 1];
    float cr = h0r[b * 64 + p], ci = h0i[b * 64 + p];
    #pragma unroll
    for (int qu = 0; qu < 4; qu++) {
        float2 e[32];
        #pragma unroll
        for (int c = 0; c < 32; c++)
            e[c] = *(const float2*)(endbuf + ((size_t)b * NC + qu * 32 + c) * 128 + 2 * p);
        #pragma unroll
        for (int c = 0; c < 32; c++) {
            int cc = qu * 32 + c;
            *(float2*)(carry + ((size_t)b * NC + cc) * 128 + 2 * p) = make_float2(cr, ci);
            float nr = fmaf(aSr, cr, fmaf(-aSi, ci, e[c].x));
            float ni = fmaf(aSr, ci, fmaf(aSi, cr, e[c].y));
            cr = nr; ci = ni;
        }
    }
}

// --------------------------------------------- GEMM 2, transposed output ----
// (R8's verified kernel; only chunk plumbing follows S_CH=64: c=l0>>6,
//  kp=(l&63)+1. Dense-segment epilogue via padded ldsF transpose.)
__global__ __launch_bounds__(256, 4) void gemm2t(const float* __restrict__ hloc,
                                                 const ushort_t* __restrict__ CeffT,
                                                 const float* __restrict__ u,
                                                 const float* __restrict__ D,
                                                 const float* __restrict__ dApow,
                                                 const float* __restrict__ carry,
                                                 float* __restrict__ y,
                                                 float* __restrict__ out_hlast) {
    __shared__ __align__(16) char smem[64 * 132 * 4];   // 33792 B
    ushort_t* Blds = (ushort_t*)smem;   // Ceff tile (32 KB), phase A
    float* ldsF = (float*)smem;         // transpose tile [64][132], phase B/C
    int tid = threadIdx.x;
    int w = tid >> 6, lane = tid & 63;
    int q = lane >> 4, mn = lane & 15;
    int swz = q ^ ((mn >> 1) & 3);
    size_t row0 = (size_t)blockIdx.x * 64;
    int b = (int)(row0 >> 13);            // batch
    int l0 = (int)(row0 & (L - 1));
    int c = l0 >> 6;                      // chunk (S_CH = 64 == block rows)

    int seq = w * 16 + mn;                // local row owned by this lane (MFMA)
    int l = l0 + seq;
    int kp = (l & (S_CH - 1)) + 1;
    const float* hrow = hloc + (row0 + seq) * 128;
    const float* prow = dApow + (size_t)kp * 128;
    const float* crow = carry + ((size_t)b * NC + c) * 128;
    bool last = (l == L - 1);

    // ---- hfix B-fragments (one seq row per lane, k-quarter q), in regs ----
    u32x4 Bf[4];
    #pragma unroll
    for (int kt = 0; kt < 4; kt++) {
        int kb = kt * 32 + q * 8;
        float4 h0 = *(const float4*)(hrow + kb);
        float4 h1 = *(const float4*)(hrow + kb + 4);
        float4 p0 = *(const float4*)(prow + kb);
        float4 p1 = *(const float4*)(prow + kb + 4);
        float4 c0 = *(const float4*)(crow + kb);
        float4 c1 = *(const float4*)(crow + kb + 4);
        float f0 = h0.x + p0.x * c0.x - p0.y * c0.y;
        float f1 = h0.y + p0.x * c0.y + p0.y * c0.x;
        float f2 = h0.z + p0.z * c0.z - p0.w * c0.w;
        float f3 = h0.w + p0.z * c0.w + p0.w * c0.z;
        float f4 = h1.x + p1.x * c1.x - p1.y * c1.y;
        float f5 = h1.y + p1.x * c1.y + p1.y * c1.x;
        float f6 = h1.z + p1.z * c1.z - p1.w * c1.w;
        float f7 = h1.w + p1.z * c1.w + p1.w * c1.z;
        Bf[kt].u[0] = cvtpk(f0, f1); Bf[kt].u[1] = cvtpk(f2, f3);
        Bf[kt].u[2] = cvtpk(f4, f5); Bf[kt].u[3] = cvtpk(f6, f7);
        if (last) {
            int pb = kb >> 1;
            out_hlast[b * 64 + pb]     = f0; out_hlast[512 + b * 64 + pb]     = f1;
            out_hlast[b * 64 + pb + 1] = f2; out_hlast[512 + b * 64 + pb + 1] = f3;
            out_hlast[b * 64 + pb + 2] = f4; out_hlast[512 + b * 64 + pb + 2] = f5;
            out_hlast[b * 64 + pb + 3] = f6; out_hlast[512 + b * 64 + pb + 3] = f7;
        }
    }

    // dense-epilogue lane mapping: rows w*16 + i*2 + (lane>>5), cols (lane&31)*4
    int erow_b = w * 16 + (lane >> 5);    // + i*2 per sub-iteration
    int es4 = lane & 31;                  // float4 column index within 128

    for (int ct = 0; ct < 8; ct++) {
        // issue-early: u for sub-iterations 0..3 (independent of all LDS)
        const float* ub = u + ct * 128 + es4 * 4;
        float4 uv0 = *(const float4*)(ub + (row0 + erow_b + 0) * 1024);
        float4 uv1 = *(const float4*)(ub + (row0 + erow_b + 2) * 1024);
        float4 uv2 = *(const float4*)(ub + (row0 + erow_b + 4) * 1024);
        float4 uv3 = *(const float4*)(ub + (row0 + erow_b + 6) * 1024);
        float4 dvv = *(const float4*)(D + ct * 128 + es4 * 4);

        if (ct) __syncthreads();          // phase-C ldsF reads of ct-1 done
        {   // stage 32KB swizzled CeffT column-tile ct
            const ushort_t* gsrc = CeffT + (size_t)ct * 16384 + w * 512 + lane * 8;
            ushort_t* ldst = Blds + w * 512;
            #pragma unroll
            for (int it = 0; it < 8; it++)
                gload_lds16(gsrc + it * 2048, ldst + it * 2048);
        }
        __syncthreads();                  // Ceff tile ready
        floatx4 acc[8] = {};
        #pragma unroll
        for (int kt = 0; kt < 4; kt++) {
            int bofs = kt * 4096 + swz * 8;
            #pragma unroll
            for (int j = 0; j < 8; j++) {
                s8v af = *(const s8v*)&Blds[bofs + (j * 16 + mn) * 32];
                acc[j] = MFMA16(af, Bf[kt].v, acc[j]);
            }
        }
        __syncthreads();                  // MFMA ds_reads done; Blds dead
        #pragma unroll
        for (int j = 0; j < 8; j++)       // dump: lane owns seq row, h j*16+q*4
            *(floatx4*)&ldsF[(size_t)seq * 132 + j * 16 + q * 4] = acc[j];
        __syncthreads();                  // ldsF ready
        #pragma unroll
        for (int i = 0; i < 8; i++) {     // dense read + u + store
            int row = erow_b + i * 2;
            float4 fv = *(const float4*)&ldsF[(size_t)row * 132 + es4 * 4];
            float4 uvv = (i == 0) ? uv0 : (i == 1) ? uv1 : (i == 2) ? uv2 :
                         (i == 3) ? uv3 :
                         *(const float4*)(ub + (row0 + row) * 1024);
            float4 o;
            o.x = fv.x + dvv.x * uvv.x;
            o.y = fv.y + dvv.y * uvv.y;
            o.z = fv.z + dvv.z * uvv.z;
            o.w = fv.w + dvv.w * uvv.w;
            *(float4*)(y + (row0 + row) * 1024 + ct * 128 + es4 * 4) = o;
        }
    }
}

// -------------------------------------------------------------- launch ----
extern "C" void kernel_launch(void* const* d_in, const int* in_sizes, int n_in,
                              void* d_out, int out_size, void* d_ws, size_t ws_size,
                              hipStream_t stream) {
    const float* u      = (const float*)d_in[0];
    const float* h_r    = (const float*)d_in[1];
    const float* h_i    = (const float*)d_in[2];
    const float* A_real = (const float*)d_in[3];
    const float* A_imag = (const float*)d_in[4];
    const float* B_real = (const float*)d_in[5];
    const float* B_imag = (const float*)d_in[6];
    const float* C_real = (const float*)d_in[7];
    const float* C_imag = (const float*)d_in[8];
    const float* D      = (const float*)d_in[9];
    const float* inv_dt = (const float*)d_in[10];
    float* out = (float*)d_out;

    // workspace layout (floats from base; all 16B aligned)
    float* wsf       = (float*)d_ws;
    float* P_params  = wsf;                    // 256 used, reserve 1024
    float* P_dApow   = wsf + 1024;             // 65*128 = 8320, reserve 16640
    float* P_carry   = wsf + 1024 + 16640;     // 8*NC*128 = 131072
    float* P_end     = P_carry + 131072;       // 131072
    ushort_t* P_W1T  = (ushort_t*)(P_end + 131072);     // 128*1024 bf16 (linear)
    ushort_t* P_Ceff = P_W1T + 128 * 1024;              // 1024*128 bf16 (swizzled)
    float* P_Bu      = (float*)(P_Ceff + 1024 * 128);   // 65536*128 f32 (33.5MB)

    params_kernel<<<1, 64, 0, stream>>>(A_real, A_imag, inv_dt, P_params, P_dApow);
    build_w<<<576, 256, 0, stream>>>(B_real, B_imag, C_real, C_imag, P_params, P_W1T, P_Ceff);
    gemm1s<<<M_TOT / 64, 256, 0, stream>>>(u, P_W1T, P_params, P_dApow, P_Bu, P_end);
    scan_carry<<<8, 64, 0, stream>>>(P_end, P_dApow, h_r, h_i, P_carry);
    gemm2t<<<M_TOT / 64, 256, 0, stream>>>(P_Bu, P_Ceff, u, D, P_dApow, P_carry,
                                           out, out + (size_t)M_TOT * H);
}